// Round 4
// baseline (502.953 us; speedup 1.0000x reference)
//
#include <hip/hip_runtime.h>
#include <hip/hip_bf16.h>
#include <math.h>

// Problem constants
#define Hh 192
#define Ww 192
#define HWp (Hh*Ww)          // 36864
#define Bb 2
#define Cch 64
#define DI 128
#define NWX 24               // windows per row
#define WPB 576              // windows per batch
#define NW  1152             // total windows
#define DS 16
#define SHIFT 4

// ------------------- K1: NCHW -> NHWC transpose -------------------
__global__ __launch_bounds__(256) void k_transpose(const float* __restrict__ x, float* __restrict__ xT){
  __shared__ float t[64][65];
  int b   = blockIdx.x / WPB;
  int hw0 = (blockIdx.x % WPB) * 64;
  int lane = threadIdx.x & 63, grp = threadIdx.x >> 6;
  const float* xb = x + (size_t)b * Cch * HWp;
  #pragma unroll
  for (int r = 0; r < 64; r += 4) {
    int c = r + grp;
    t[c][lane] = xb[(size_t)c * HWp + hw0 + lane];
  }
  __syncthreads();
  float* xo = xT + ((size_t)b * HWp + hw0) * 64;
  #pragma unroll
  for (int r = 0; r < 64; r += 4) {
    int hwl = r + grp;
    xo[(size_t)hwl * 64 + lane] = t[lane][hwl];
  }
}

// ------------------- K2: shift + LN1 + in_proj + mask + conv1d + silu -------------------
__global__ __launch_bounds__(256) void k_stage1(
    const float* __restrict__ xT, const float* __restrict__ g1, const float* __restrict__ b1,
    const float* __restrict__ in_w, const float* __restrict__ in_b,
    const float* __restrict__ conv_w, const float* __restrict__ conv_b,
    float* __restrict__ xc, float* __restrict__ Zb){
  __shared__ __align__(16) float xs[64][68];
  int n = blockIdx.x;
  int b = n / WPB, wi = n % WPB;
  int wy = wi / NWX, wx = wi % NWX;
  int tid = threadIdx.x;
  int l = tid >> 2, q = tid & 3;       // token l (0..63), quarter q
  int iy = l >> 3, ix = l & 7;
  int h = wy*8 + iy, w = wx*8 + ix;    // shifted-space coords
  int hs = h + SHIFT; if (hs >= Hh) hs -= Hh;
  int ws2 = w + SHIFT; if (ws2 >= Ww) ws2 -= Ww;
  const float* src = xT + ((size_t)b*HWp + (size_t)hs*Ww + ws2) * 64 + q*16;
  float v[16];
  float s1 = 0.f, s2 = 0.f;
  #pragma unroll
  for (int k = 0; k < 4; k++) {
    float4 f = *reinterpret_cast<const float4*>(src + k*4);
    v[k*4+0]=f.x; v[k*4+1]=f.y; v[k*4+2]=f.z; v[k*4+3]=f.w;
  }
  #pragma unroll
  for (int i = 0; i < 16; i++) { s1 += v[i]; s2 += v[i]*v[i]; }
  s1 += __shfl_xor(s1, 1); s2 += __shfl_xor(s2, 1);
  s1 += __shfl_xor(s1, 2); s2 += __shfl_xor(s2, 2);
  float mu = s1 * (1.f/64.f);
  float var = s2 * (1.f/64.f) - mu*mu;
  float rstd = rsqrtf(var + 1e-5f);
  #pragma unroll
  for (int i = 0; i < 16; i++) {
    int c = q*16 + i;
    xs[l][c] = (v[i]-mu)*rstd*g1[c] + b1[c];
  }
  __syncthreads();
  // GEMM: 64 tokens x (64 -> 256). thread owns output column o = tid.
  int o = tid;
  float bias = in_b[o];
  int dd = o & 127;
  float cw0 = conv_w[dd], cw1 = conv_w[128+dd], cw2 = conv_w[256+dd], cw3 = conv_w[384+dd];
  float cb = conv_b[dd];
  float p1 = 0.f, p2 = 0.f, p3 = 0.f;
  for (int lc = 0; lc < 64; lc += 8) {
    float acc[8] = {0.f,0.f,0.f,0.f,0.f,0.f,0.f,0.f};
    for (int c = 0; c < 64; c++) {
      float wv = in_w[c*256 + o];
      #pragma unroll
      for (int j = 0; j < 8; j++) acc[j] += xs[lc+j][c] * wv;
    }
    if (o < 128) {
      #pragma unroll
      for (int j = 0; j < 8; j++) {
        int l2 = lc + j;
        int hh = wy*8 + (l2>>3), ww2 = wx*8 + (l2&7);
        float m = (hh < Hh-SHIFT && ww2 < Ww-SHIFT) ? 1.f : 0.f;
        float xv = (acc[j] + bias) * m;      // masked x_in
        float pre = cw3*xv + cw2*p1 + cw1*p2 + cw0*p3 + cb;
        xc[((size_t)n*64 + l2)*128 + o] = pre / (1.f + __expf(-pre));  // silu
        p3 = p2; p2 = p1; p1 = xv;
      }
    } else {
      #pragma unroll
      for (int j = 0; j < 8; j++)
        Zb[((size_t)n*64 + lc + j)*128 + (o-128)] = acc[j] + bias;
    }
  }
}

// ------------------- K3: fused dbc GEMM + dt + selective scan + gate -------------------
// 512 threads: d = tid>>2 (0..127), sq = tid&3 owns states sq*4..sq*4+3.
// dbc computed into LDS (never hits global). y written in-place over xc tile in LDS.
__global__ __launch_bounds__(512) void k_scanf(
    float* __restrict__ xc,           // in: xc ; out: g = (y + D*xc)*silu(z)
    const float* __restrict__ Zb, const float* __restrict__ xproj_w,
    const float* __restrict__ dt_w, const float* __restrict__ dt_b,
    const float* __restrict__ A_log, const float* __restrict__ Dp){
  __shared__ __align__(16) float xs[64][132];   // xc tile -> later y tile
  __shared__ float wsx[128][40];                // xproj weights
  __shared__ float dbc_s[64][40];               // per-token dt(4) B(16) C(16)
  int n = blockIdx.x;
  int tid = threadIdx.x;
  const float4* src = reinterpret_cast<const float4*>(xc + (size_t)n*8192);
  #pragma unroll
  for (int k = 0; k < 4; k++) {
    int gi = tid + k*512;
    int t = gi >> 5, q = gi & 31;
    *reinterpret_cast<float4*>(&xs[t][q*4]) = src[gi];
  }
  for (int idx = tid; idx < 4608; idx += 512) {
    int c = idx / 36, j = idx - c*36;
    wsx[c][j] = xproj_w[idx];
  }
  __syncthreads();
  // dbc GEMM: 64 tokens x 36 outs; 8 threads/token, 5 outs each (cols 36..39 junk, never read)
  {
    int l = tid >> 3, j0 = (tid & 7) * 5;
    float acc[5] = {0.f,0.f,0.f,0.f,0.f};
    for (int c = 0; c < 128; c++) {
      float xv = xs[l][c];
      #pragma unroll
      for (int u = 0; u < 5; u++) acc[u] += xv * wsx[c][j0+u];
    }
    #pragma unroll
    for (int u = 0; u < 5; u++) dbc_s[l][j0+u] = acc[u];
  }
  __syncthreads();
  // scan: quad of lanes per channel d, 4 states per lane
  int d = tid >> 2, sq = tid & 3;
  int s0 = sq*4;
  float a0 = -__expf(A_log[d*16+s0+0]);
  float a1 = -__expf(A_log[d*16+s0+1]);
  float a2 = -__expf(A_log[d*16+s0+2]);
  float a3 = -__expf(A_log[d*16+s0+3]);
  float dtb = dt_b[d];
  float dtw0 = dt_w[d], dtw1 = dt_w[128+d], dtw2 = dt_w[256+d], dtw3 = dt_w[384+d];
  float Dd = Dp[d];
  float h0=0.f, h1=0.f, h2=0.f, h3=0.f;
  #pragma unroll 4
  for (int i = 0; i < 64; i++) {
    float pre = dtb + dbc_s[i][0]*dtw0 + dbc_s[i][1]*dtw1 + dbc_s[i][2]*dtw2 + dbc_s[i][3]*dtw3;
    float dtv = (pre > 20.f) ? pre : log1pf(__expf(pre));  // softplus
    float xcv = xs[i][d];
    float du = dtv * xcv;
    h0 = __expf(dtv*a0)*h0 + du*dbc_s[i][4+s0+0];
    h1 = __expf(dtv*a1)*h1 + du*dbc_s[i][4+s0+1];
    h2 = __expf(dtv*a2)*h2 + du*dbc_s[i][4+s0+2];
    h3 = __expf(dtv*a3)*h3 + du*dbc_s[i][4+s0+3];
    float y = h0*dbc_s[i][20+s0+0] + h1*dbc_s[i][20+s0+1]
            + h2*dbc_s[i][20+s0+2] + h3*dbc_s[i][20+s0+3];
    y += __shfl_xor(y, 1);
    y += __shfl_xor(y, 2);
    if (sq == 0) xs[i][d] = y + Dd*xcv;   // overwrite consumed xc slot
  }
  __syncthreads();
  // gating epilogue: g = y * silu(z), vectorized
  const float4* zsrc = reinterpret_cast<const float4*>(Zb + (size_t)n*8192);
  float4* dst = reinterpret_cast<float4*>(xc + (size_t)n*8192);
  #pragma unroll
  for (int k = 0; k < 4; k++) {
    int gi = tid + k*512;
    int t = gi >> 5, q = gi & 31;
    float4 yv = *reinterpret_cast<const float4*>(&xs[t][q*4]);
    float4 zv = zsrc[gi];
    float4 g;
    g.x = yv.x * (zv.x / (1.f + __expf(-zv.x)));
    g.y = yv.y * (zv.y / (1.f + __expf(-zv.y)));
    g.z = yv.z * (zv.z / (1.f + __expf(-zv.z)));
    g.w = yv.w * (zv.w / (1.f + __expf(-zv.w)));
    dst[gi] = g;
  }
}

// ------------------- K5: out_proj + window-reverse + skip1 + LN2 -------------------
__global__ __launch_bounds__(256) void k_out(
    const float* __restrict__ xT, const float* __restrict__ g,
    const float* __restrict__ out_w, const float* __restrict__ out_b,
    const float* __restrict__ skip1, const float* __restrict__ g2, const float* __restrict__ b2,
    float* __restrict__ x1, float* __restrict__ x2){
  __shared__ __align__(16) float gs[64][132];
  __shared__ float outs[64][65];
  int n = blockIdx.x;
  int b = n / WPB, wi = n % WPB;
  int wy = wi / NWX, wx = wi % NWX;
  const float4* src = reinterpret_cast<const float4*>(g + (size_t)n*8192);
  #pragma unroll
  for (int k = 0; k < 8; k++) {
    int gi = threadIdx.x + k*256;
    int t = gi >> 5, d4 = gi & 31;
    *reinterpret_cast<float4*>(&gs[t][d4*4]) = src[gi];
  }
  __syncthreads();
  int o = threadIdx.x & 63, tg = threadIdx.x >> 6;
  float acc[16];
  #pragma unroll
  for (int i = 0; i < 16; i++) acc[i] = 0.f;
  for (int c = 0; c < 128; c++) {
    float wv = out_w[c*64 + o];
    #pragma unroll
    for (int i = 0; i < 16; i++) acc[i] += gs[tg*16 + i][c] * wv;
  }
  float obv = out_b[o];
  #pragma unroll
  for (int i = 0; i < 16; i++) outs[tg*16 + i][o] = acc[i] + obv;
  __syncthreads();
  // LN per token (4 lanes per token, 16 ch each)
  int l = threadIdx.x >> 2, q = threadIdx.x & 3;
  int hh = wy*8 + (l>>3), ww2 = wx*8 + (l&7);
  size_t T = (size_t)b*HWp + (size_t)hh*Ww + ww2;
  float v[16];
  float s1 = 0.f, s2 = 0.f;
  #pragma unroll
  for (int i = 0; i < 16; i++) {
    int c = q*16 + i;
    float val = xT[T*64 + c] * skip1[c] + outs[l][c];
    v[i] = val; s1 += val; s2 += val*val;
  }
  s1 += __shfl_xor(s1, 1); s2 += __shfl_xor(s2, 1);
  s1 += __shfl_xor(s1, 2); s2 += __shfl_xor(s2, 2);
  float mu = s1*(1.f/64.f);
  float var = s2*(1.f/64.f) - mu*mu;
  float rstd = rsqrtf(var + 1e-5f);
  #pragma unroll
  for (int i = 0; i < 16; i++) {
    int c = q*16 + i;
    x1[T*64 + c] = v[i];
    x2[T*64 + c] = (v[i]-mu)*rstd*g2[c] + b2[c];
  }
}

// ------------------- K6: CAB conv1 3x3 64->16 + gelu (LDS-staged weights) -------------------
__global__ __launch_bounds__(256) void k_conv1(
    const float* __restrict__ x2, const float* __restrict__ w1, const float* __restrict__ bc1,
    float* __restrict__ c1){
  __shared__ float xt[100][68];      // 10x10 pixels x 64 ch (pad 68) = 27.2 KB
  __shared__ float w_s[9][64][16];   // [tap][ci][co] = 36.9 KB
  int b = blockIdx.x / WPB;
  int r = blockIdx.x % WPB;
  int by = r / NWX, bx = r % NWX;
  for (int idx = threadIdx.x; idx < 9216; idx += 256) {
    int co = idx & 15, ci = (idx >> 4) & 63, tap = idx >> 10;
    w_s[tap][ci][co] = w1[(co*64 + ci)*9 + tap];
  }
  int lane = threadIdx.x & 63, grp = threadIdx.x >> 6;
  for (int p = grp; p < 100; p += 4) {
    int gy = by*8 + p/10 - 1;
    int gx = bx*8 + p%10 - 1;
    float val = 0.f;
    if (gy >= 0 && gy < Hh && gx >= 0 && gx < Ww)
      val = x2[((size_t)b*HWp + (size_t)gy*Ww + gx)*64 + lane];
    xt[p][lane] = val;
  }
  __syncthreads();
  int co = threadIdx.x & 15;
  int pp = threadIdx.x >> 4;   // 0..15
  int px = pp & 7, py0 = pp >> 3;
  float acc[4] = {0.f,0.f,0.f,0.f};
  #pragma unroll
  for (int tap = 0; tap < 9; tap++) {
    int ky = tap / 3, kx = tap % 3;
    const float* x0  = &xt[(py0+0+ky)*10 + px+kx][0];
    const float* x1p = &xt[(py0+2+ky)*10 + px+kx][0];
    const float* x2p = &xt[(py0+4+ky)*10 + px+kx][0];
    const float* x3p = &xt[(py0+6+ky)*10 + px+kx][0];
    #pragma unroll 4
    for (int ci = 0; ci < 64; ci++) {
      float wv = w_s[tap][ci][co];
      acc[0] += x0[ci]  * wv;
      acc[1] += x1p[ci] * wv;
      acc[2] += x2p[ci] * wv;
      acc[3] += x3p[ci] * wv;
    }
  }
  float bias = bc1[co];
  #pragma unroll
  for (int j = 0; j < 4; j++) {
    int py = py0 + 2*j;
    float v = acc[j] + bias;
    float gv = 0.5f * v * (1.f + erff(v * 0.70710678118f));
    c1[((size_t)b*HWp + (size_t)(by*8+py)*Ww + bx*8+px)*16 + co] = gv;
  }
}

// ------------------- K7: CAB conv2 3x3 16->64 + partial mean (LDS-staged weights) -------------------
__global__ __launch_bounds__(256) void k_conv2(
    const float* __restrict__ c1, const float* __restrict__ w2, const float* __restrict__ bc2,
    float* __restrict__ c2, float* __restrict__ sums){
  __shared__ float xt[100][17];      // 6.8 KB
  __shared__ float w_s[9][16][64];   // [tap][ci][co] = 36.9 KB
  __shared__ float red[4][64];
  int b = blockIdx.x / WPB;
  int r = blockIdx.x % WPB;
  int by = r / NWX, bx = r % NWX;
  for (int idx = threadIdx.x; idx < 9216; idx += 256) {
    int co = idx & 63, ci = (idx >> 6) & 15, tap = idx >> 10;
    w_s[tap][ci][co] = w2[(co*16 + ci)*9 + tap];
  }
  for (int idx = threadIdx.x; idx < 1600; idx += 256) {
    int p = idx >> 4, ci = idx & 15;
    int gy = by*8 + p/10 - 1;
    int gx = bx*8 + p%10 - 1;
    float val = 0.f;
    if (gy >= 0 && gy < Hh && gx >= 0 && gx < Ww)
      val = c1[((size_t)b*HWp + (size_t)gy*Ww + gx)*16 + ci];
    xt[p][ci] = val;
  }
  __syncthreads();
  int co = threadIdx.x & 63;
  int pg = threadIdx.x >> 6;   // 0..3 -> pixels pg*16 .. pg*16+15
  float acc[16];
  #pragma unroll
  for (int j = 0; j < 16; j++) acc[j] = 0.f;
  #pragma unroll
  for (int tap = 0; tap < 9; tap++) {
    int ky = tap / 3, kx = tap % 3;
    #pragma unroll
    for (int ci = 0; ci < 16; ci++) {
      float wv = w_s[tap][ci][co];
      #pragma unroll
      for (int j = 0; j < 16; j++) {
        int pp = pg*16 + j;
        int py = pp >> 3, px = pp & 7;
        acc[j] += xt[(py+ky)*10 + px+kx][ci] * wv;
      }
    }
  }
  float bias = bc2[co];
  float lsum = 0.f;
  #pragma unroll
  for (int j = 0; j < 16; j++) {
    int pp = pg*16 + j;
    int py = pp >> 3, px = pp & 7;
    float v = acc[j] + bias;
    c2[((size_t)b*HWp + (size_t)(by*8+py)*Ww + bx*8+px)*64 + co] = v;
    lsum += v;
  }
  red[pg][co] = lsum;
  __syncthreads();
  if (threadIdx.x < 64) {
    float s = red[0][threadIdx.x] + red[1][threadIdx.x] + red[2][threadIdx.x] + red[3][threadIdx.x];
    atomicAdd(&sums[b*64 + threadIdx.x], s);
  }
}

// ------------------- K8: channel attention -------------------
__global__ void k_att(const float* __restrict__ sums,
                      const float* __restrict__ wd, const float* __restrict__ bd,
                      const float* __restrict__ wu, const float* __restrict__ bu,
                      float* __restrict__ att){
  int tid = threadIdx.x;            // 128 threads
  int b = tid >> 6, co = tid & 63;
  float inv = 1.f / (float)HWp;
  float hid[4];
  #pragma unroll
  for (int j = 0; j < 4; j++) {
    float acc = bd[j];
    for (int c = 0; c < 64; c++) acc += wd[j*64+c] * (sums[b*64+c] * inv);
    hid[j] = fmaxf(acc, 0.f);
  }
  float acc = bu[co];
  #pragma unroll
  for (int j = 0; j < 4; j++) acc += wu[co*4+j] * hid[j];
  att[tid] = 1.f / (1.f + __expf(-acc));
}

// ------------------- K9: final combine + NHWC -> NCHW -------------------
__global__ __launch_bounds__(256) void k_final(
    const float* __restrict__ x1, const float* __restrict__ c2,
    const float* __restrict__ skip2, const float* __restrict__ att,
    float* __restrict__ out){
  __shared__ float t[64][65];
  int b = blockIdx.x / WPB;
  int hw0 = (blockIdx.x % WPB) * 64;
  int lane = threadIdx.x & 63, grp = threadIdx.x >> 6;
  float sk = skip2[lane], at = att[b*64 + lane];
  #pragma unroll
  for (int r = 0; r < 64; r += 4) {
    int hwl = r + grp;
    size_t T = (size_t)b*HWp + hw0 + hwl;
    t[hwl][lane] = x1[T*64+lane]*sk + c2[T*64+lane]*at;
  }
  __syncthreads();
  float* ob = out + (size_t)b * Cch * HWp;
  #pragma unroll
  for (int r = 0; r < 64; r += 4) {
    int c = r + grp;
    ob[(size_t)c*HWp + hw0 + lane] = t[lane][c];
  }
}

extern "C" void kernel_launch(void* const* d_in, const int* in_sizes, int n_in,
                              void* d_out, int out_size, void* d_ws, size_t ws_size,
                              hipStream_t stream) {
  (void)in_sizes; (void)n_in; (void)out_size; (void)ws_size;
  const float* x      = (const float*)d_in[0];
  const float* ln1_g  = (const float*)d_in[1];
  const float* ln1_b  = (const float*)d_in[2];
  const float* in_w   = (const float*)d_in[3];
  const float* in_b   = (const float*)d_in[4];
  const float* conv_w = (const float*)d_in[5];
  const float* conv_b = (const float*)d_in[6];
  const float* xproj_w= (const float*)d_in[7];
  const float* dt_w   = (const float*)d_in[8];
  const float* dt_b   = (const float*)d_in[9];
  const float* A_log  = (const float*)d_in[10];
  const float* Dp     = (const float*)d_in[11];
  const float* out_w  = (const float*)d_in[12];
  const float* out_b  = (const float*)d_in[13];
  const float* skip1  = (const float*)d_in[14];
  const float* ln2_g  = (const float*)d_in[15];
  const float* ln2_b  = (const float*)d_in[16];
  const float* skip2  = (const float*)d_in[17];
  const float* cab_w1 = (const float*)d_in[18];
  const float* cab_b1 = (const float*)d_in[19];
  const float* cab_w2 = (const float*)d_in[20];
  const float* cab_b2 = (const float*)d_in[21];
  const float* ca_wd  = (const float*)d_in[22];
  const float* ca_bd  = (const float*)d_in[23];
  const float* ca_wu  = (const float*)d_in[24];
  const float* ca_bu  = (const float*)d_in[25];

  float* ws   = (float*)d_ws;
  float* xT   = ws;                        // [0, 4718592)
  float* xc   = ws + 4718592;              // [4718592, 14155776)  g in-place; c2 aliases later
  float* z    = ws + 14155776;             // [14155776, 23592960) x1/x2 alias later
  float* c1   = ws + 23592960;             // [23592960, ...) conv1 output
  float* sums = ws + 26247168;             // 128
  float* att  = ws + 26247296;             // 128
  float* x1   = ws + 14155776;             // alias over z (z dead after k_scanf)
  float* x2   = ws + 18874368;             // alias over z second half
  float* c2   = ws + 4718592;              // alias over xc/g (dead after k_out)

  hipMemsetAsync(sums, 0, 128*sizeof(float), stream);
  k_transpose<<<NW, 256, 0, stream>>>(x, xT);
  k_stage1<<<NW, 256, 0, stream>>>(xT, ln1_g, ln1_b, in_w, in_b, conv_w, conv_b, xc, z);
  k_scanf<<<NW, 512, 0, stream>>>(xc, z, xproj_w, dt_w, dt_b, A_log, Dp);
  k_out<<<NW, 256, 0, stream>>>(xT, xc, out_w, out_b, skip1, ln2_g, ln2_b, x1, x2);
  k_conv1<<<NW, 256, 0, stream>>>(x2, cab_w1, cab_b1, c1);
  k_conv2<<<NW, 256, 0, stream>>>(c1, cab_w2, cab_b2, c2, sums);
  k_att<<<1, 128, 0, stream>>>(sums, ca_wd, ca_bd, ca_wu, ca_bu, att);
  k_final<<<NW, 256, 0, stream>>>(x1, c2, skip2, att, (float*)d_out);
}

// Round 5
// 416.651 us; speedup vs baseline: 1.2071x; 1.2071x over previous
//
#include <hip/hip_runtime.h>
#include <hip/hip_bf16.h>
#include <math.h>

// Problem constants
#define Hh 192
#define Ww 192
#define HWp (Hh*Ww)          // 36864
#define Bb 2
#define Cch 64
#define DI 128
#define NWX 24               // windows per row
#define WPB 576              // windows per batch
#define NW  1152             // total windows
#define DS 16
#define SHIFT 4

// ------------------- K1: NCHW -> NHWC transpose -------------------
__global__ __launch_bounds__(256) void k_transpose(const float* __restrict__ x, float* __restrict__ xT){
  __shared__ float t[64][65];
  int b   = blockIdx.x / WPB;
  int hw0 = (blockIdx.x % WPB) * 64;
  int lane = threadIdx.x & 63, grp = threadIdx.x >> 6;
  const float* xb = x + (size_t)b * Cch * HWp;
  #pragma unroll
  for (int r = 0; r < 64; r += 4) {
    int c = r + grp;
    t[c][lane] = xb[(size_t)c * HWp + hw0 + lane];
  }
  __syncthreads();
  float* xo = xT + ((size_t)b * HWp + hw0) * 64;
  #pragma unroll
  for (int r = 0; r < 64; r += 4) {
    int hwl = r + grp;
    xo[(size_t)hwl * 64 + lane] = t[lane][hwl];
  }
}

// ------------------- K2: shift + LN1 + in_proj + mask + conv1d + silu -------------------
__global__ __launch_bounds__(256) void k_stage1(
    const float* __restrict__ xT, const float* __restrict__ g1, const float* __restrict__ b1,
    const float* __restrict__ in_w, const float* __restrict__ in_b,
    const float* __restrict__ conv_w, const float* __restrict__ conv_b,
    float* __restrict__ xc, float* __restrict__ Zb){
  __shared__ __align__(16) float xs[64][68];
  int n = blockIdx.x;
  int b = n / WPB, wi = n % WPB;
  int wy = wi / NWX, wx = wi % NWX;
  int tid = threadIdx.x;
  int l = tid >> 2, q = tid & 3;       // token l (0..63), quarter q
  int iy = l >> 3, ix = l & 7;
  int h = wy*8 + iy, w = wx*8 + ix;    // shifted-space coords
  int hs = h + SHIFT; if (hs >= Hh) hs -= Hh;
  int ws2 = w + SHIFT; if (ws2 >= Ww) ws2 -= Ww;
  const float* src = xT + ((size_t)b*HWp + (size_t)hs*Ww + ws2) * 64 + q*16;
  float v[16];
  float s1 = 0.f, s2 = 0.f;
  #pragma unroll
  for (int k = 0; k < 4; k++) {
    float4 f = *reinterpret_cast<const float4*>(src + k*4);
    v[k*4+0]=f.x; v[k*4+1]=f.y; v[k*4+2]=f.z; v[k*4+3]=f.w;
  }
  #pragma unroll
  for (int i = 0; i < 16; i++) { s1 += v[i]; s2 += v[i]*v[i]; }
  s1 += __shfl_xor(s1, 1); s2 += __shfl_xor(s2, 1);
  s1 += __shfl_xor(s1, 2); s2 += __shfl_xor(s2, 2);
  float mu = s1 * (1.f/64.f);
  float var = s2 * (1.f/64.f) - mu*mu;
  float rstd = rsqrtf(var + 1e-5f);
  #pragma unroll
  for (int i = 0; i < 16; i++) {
    int c = q*16 + i;
    xs[l][c] = (v[i]-mu)*rstd*g1[c] + b1[c];
  }
  __syncthreads();
  // GEMM: 64 tokens x (64 -> 256). thread owns output column o = tid.
  int o = tid;
  float bias = in_b[o];
  int dd = o & 127;
  float cw0 = conv_w[dd], cw1 = conv_w[128+dd], cw2 = conv_w[256+dd], cw3 = conv_w[384+dd];
  float cb = conv_b[dd];
  float p1 = 0.f, p2 = 0.f, p3 = 0.f;
  for (int lc = 0; lc < 64; lc += 8) {
    float acc[8] = {0.f,0.f,0.f,0.f,0.f,0.f,0.f,0.f};
    for (int c = 0; c < 64; c++) {
      float wv = in_w[c*256 + o];
      #pragma unroll
      for (int j = 0; j < 8; j++) acc[j] += xs[lc+j][c] * wv;
    }
    if (o < 128) {
      #pragma unroll
      for (int j = 0; j < 8; j++) {
        int l2 = lc + j;
        int hh = wy*8 + (l2>>3), ww2 = wx*8 + (l2&7);
        float m = (hh < Hh-SHIFT && ww2 < Ww-SHIFT) ? 1.f : 0.f;
        float xv = (acc[j] + bias) * m;      // masked x_in
        float pre = cw3*xv + cw2*p1 + cw1*p2 + cw0*p3 + cb;
        xc[((size_t)n*64 + l2)*128 + o] = pre / (1.f + __expf(-pre));  // silu
        p3 = p2; p2 = p1; p1 = xv;
      }
    } else {
      #pragma unroll
      for (int j = 0; j < 8; j++)
        Zb[((size_t)n*64 + lc + j)*128 + (o-128)] = acc[j] + bias;
    }
  }
}

// ------------------- K3: fused dbc GEMM + dt + selective scan + gate -------------------
// 512 threads: d = tid>>2 (0..127), sq = tid&3 owns states sq*4..sq*4+3.
// Lean inner loop: 3x ds_read_b128 + 1 b32, cheap softplus, 5 exps/step.
__global__ __launch_bounds__(512) void k_scanf(
    float* __restrict__ xc,           // in: xc ; out: g = (y + D*xc)*silu(z)
    const float* __restrict__ Zb, const float* __restrict__ xproj_w,
    const float* __restrict__ dt_w, const float* __restrict__ dt_b,
    const float* __restrict__ A_log, const float* __restrict__ Dp){
  __shared__ __align__(16) float xs[64][132];   // xc tile -> later y tile (33.8 KB)
  __shared__ __align__(16) float wsT[36][140];  // xproj transposed [j][c] (20.2 KB)
  __shared__ __align__(16) float dbc_s[64][40]; // per-token dt(4) B(16) C(16) (10.2 KB)
  int n = blockIdx.x;
  int tid = threadIdx.x;
  const float4* src = reinterpret_cast<const float4*>(xc + (size_t)n*8192);
  #pragma unroll
  for (int k = 0; k < 4; k++) {
    int gi = tid + k*512;
    int t = gi >> 5, q = gi & 31;
    *reinterpret_cast<float4*>(&xs[t][q*4]) = src[gi];
  }
  for (int idx = tid; idx < 4608; idx += 512) {
    int c = idx / 36, j = idx - c*36;
    wsT[j][c] = xproj_w[idx];
  }
  __syncthreads();
  // dbc GEMM: token t = tid>>3, j-slots j8, j8+8, ..., (j8+32 if j8<4)
  {
    int t = tid >> 3, j8 = tid & 7;
    float acc[5] = {0.f,0.f,0.f,0.f,0.f};
    for (int c0 = 0; c0 < 128; c0 += 4) {
      float4 xv = *reinterpret_cast<const float4*>(&xs[t][c0]);
      #pragma unroll
      for (int u = 0; u < 5; u++) {
        int j = j8 + u*8;
        if (j < 36) {
          float4 wv = *reinterpret_cast<const float4*>(&wsT[j][c0]);
          acc[u] += xv.x*wv.x + xv.y*wv.y + xv.z*wv.z + xv.w*wv.w;
        }
      }
    }
    #pragma unroll
    for (int u = 0; u < 5; u++) {
      int j = j8 + u*8;
      if (j < 36) dbc_s[t][j] = acc[u];
    }
  }
  __syncthreads();
  // scan: quad of lanes per channel d, 4 states per lane
  int d = tid >> 2, sq = tid & 3;
  int s0 = sq*4;
  float a0 = -__expf(A_log[d*16+s0+0]);
  float a1 = -__expf(A_log[d*16+s0+1]);
  float a2 = -__expf(A_log[d*16+s0+2]);
  float a3 = -__expf(A_log[d*16+s0+3]);
  float dtb = dt_b[d];
  float dtw0 = dt_w[d], dtw1 = dt_w[128+d], dtw2 = dt_w[256+d], dtw3 = dt_w[384+d];
  float Dd = Dp[d];
  float h0=0.f, h1=0.f, h2=0.f, h3=0.f;
  #pragma unroll 4
  for (int i = 0; i < 64; i++) {
    float4 dv = *reinterpret_cast<const float4*>(&dbc_s[i][0]);
    float pre = dtb + dv.x*dtw0 + dv.y*dtw1 + dv.z*dtw2 + dv.w*dtw3;
    float e = __expf(pre);
    float dtv = (pre > 15.f) ? pre : __logf(1.f + e);  // cheap softplus
    float xcv = xs[i][d];
    float du = dtv * xcv;
    float4 Bv = *reinterpret_cast<const float4*>(&dbc_s[i][4+s0]);
    float4 Cv = *reinterpret_cast<const float4*>(&dbc_s[i][20+s0]);
    h0 = __expf(dtv*a0)*h0 + du*Bv.x;
    h1 = __expf(dtv*a1)*h1 + du*Bv.y;
    h2 = __expf(dtv*a2)*h2 + du*Bv.z;
    h3 = __expf(dtv*a3)*h3 + du*Bv.w;
    float y = h0*Cv.x + h1*Cv.y + h2*Cv.z + h3*Cv.w;
    y += __shfl_xor(y, 1);
    y += __shfl_xor(y, 2);
    if (sq == 0) xs[i][d] = y + Dd*xcv;   // overwrite consumed xc slot
  }
  __syncthreads();
  // gating epilogue: g = y * silu(z), vectorized
  const float4* zsrc = reinterpret_cast<const float4*>(Zb + (size_t)n*8192);
  float4* dst = reinterpret_cast<float4*>(xc + (size_t)n*8192);
  #pragma unroll
  for (int k = 0; k < 4; k++) {
    int gi = tid + k*512;
    int t = gi >> 5, q = gi & 31;
    float4 yv = *reinterpret_cast<const float4*>(&xs[t][q*4]);
    float4 zv = zsrc[gi];
    float4 g;
    g.x = yv.x * (zv.x / (1.f + __expf(-zv.x)));
    g.y = yv.y * (zv.y / (1.f + __expf(-zv.y)));
    g.z = yv.z * (zv.z / (1.f + __expf(-zv.z)));
    g.w = yv.w * (zv.w / (1.f + __expf(-zv.w)));
    dst[gi] = g;
  }
}

// ------------------- K5: out_proj + window-reverse + skip1 + LN2 -------------------
__global__ __launch_bounds__(256) void k_out(
    const float* __restrict__ xT, const float* __restrict__ g,
    const float* __restrict__ out_w, const float* __restrict__ out_b,
    const float* __restrict__ skip1, const float* __restrict__ g2, const float* __restrict__ b2,
    float* __restrict__ x1, float* __restrict__ x2){
  __shared__ __align__(16) float gs[64][132];
  __shared__ float outs[64][65];
  int n = blockIdx.x;
  int b = n / WPB, wi = n % WPB;
  int wy = wi / NWX, wx = wi % NWX;
  const float4* src = reinterpret_cast<const float4*>(g + (size_t)n*8192);
  #pragma unroll
  for (int k = 0; k < 8; k++) {
    int gi = threadIdx.x + k*256;
    int t = gi >> 5, d4 = gi & 31;
    *reinterpret_cast<float4*>(&gs[t][d4*4]) = src[gi];
  }
  __syncthreads();
  int o = threadIdx.x & 63, tg = threadIdx.x >> 6;
  float acc[16];
  #pragma unroll
  for (int i = 0; i < 16; i++) acc[i] = 0.f;
  for (int c = 0; c < 128; c++) {
    float wv = out_w[c*64 + o];
    #pragma unroll
    for (int i = 0; i < 16; i++) acc[i] += gs[tg*16 + i][c] * wv;
  }
  float obv = out_b[o];
  #pragma unroll
  for (int i = 0; i < 16; i++) outs[tg*16 + i][o] = acc[i] + obv;
  __syncthreads();
  // LN per token (4 lanes per token, 16 ch each)
  int l = threadIdx.x >> 2, q = threadIdx.x & 3;
  int hh = wy*8 + (l>>3), ww2 = wx*8 + (l&7);
  size_t T = (size_t)b*HWp + (size_t)hh*Ww + ww2;
  float v[16];
  float s1 = 0.f, s2 = 0.f;
  #pragma unroll
  for (int i = 0; i < 16; i++) {
    int c = q*16 + i;
    float val = xT[T*64 + c] * skip1[c] + outs[l][c];
    v[i] = val; s1 += val; s2 += val*val;
  }
  s1 += __shfl_xor(s1, 1); s2 += __shfl_xor(s2, 1);
  s1 += __shfl_xor(s1, 2); s2 += __shfl_xor(s2, 2);
  float mu = s1*(1.f/64.f);
  float var = s2*(1.f/64.f) - mu*mu;
  float rstd = rsqrtf(var + 1e-5f);
  #pragma unroll
  for (int i = 0; i < 16; i++) {
    int c = q*16 + i;
    x1[T*64 + c] = v[i];
    x2[T*64 + c] = (v[i]-mu)*rstd*g2[c] + b2[c];
  }
}

// ------------------- K6: CAB conv1 3x3 64->16 + gelu (LDS-staged weights) -------------------
__global__ __launch_bounds__(256) void k_conv1(
    const float* __restrict__ x2, const float* __restrict__ w1, const float* __restrict__ bc1,
    float* __restrict__ c1){
  __shared__ float xt[100][68];      // 10x10 pixels x 64 ch (pad 68) = 27.2 KB
  __shared__ float w_s[9][64][16];   // [tap][ci][co] = 36.9 KB
  int b = blockIdx.x / WPB;
  int r = blockIdx.x % WPB;
  int by = r / NWX, bx = r % NWX;
  for (int idx = threadIdx.x; idx < 9216; idx += 256) {
    int co = idx & 15, ci = (idx >> 4) & 63, tap = idx >> 10;
    w_s[tap][ci][co] = w1[(co*64 + ci)*9 + tap];
  }
  int lane = threadIdx.x & 63, grp = threadIdx.x >> 6;
  for (int p = grp; p < 100; p += 4) {
    int gy = by*8 + p/10 - 1;
    int gx = bx*8 + p%10 - 1;
    float val = 0.f;
    if (gy >= 0 && gy < Hh && gx >= 0 && gx < Ww)
      val = x2[((size_t)b*HWp + (size_t)gy*Ww + gx)*64 + lane];
    xt[p][lane] = val;
  }
  __syncthreads();
  int co = threadIdx.x & 15;
  int pp = threadIdx.x >> 4;   // 0..15
  int px = pp & 7, py0 = pp >> 3;
  float acc[4] = {0.f,0.f,0.f,0.f};
  #pragma unroll
  for (int tap = 0; tap < 9; tap++) {
    int ky = tap / 3, kx = tap % 3;
    const float* x0  = &xt[(py0+0+ky)*10 + px+kx][0];
    const float* x1p = &xt[(py0+2+ky)*10 + px+kx][0];
    const float* x2p = &xt[(py0+4+ky)*10 + px+kx][0];
    const float* x3p = &xt[(py0+6+ky)*10 + px+kx][0];
    #pragma unroll 4
    for (int ci = 0; ci < 64; ci++) {
      float wv = w_s[tap][ci][co];
      acc[0] += x0[ci]  * wv;
      acc[1] += x1p[ci] * wv;
      acc[2] += x2p[ci] * wv;
      acc[3] += x3p[ci] * wv;
    }
  }
  float bias = bc1[co];
  #pragma unroll
  for (int j = 0; j < 4; j++) {
    int py = py0 + 2*j;
    float v = acc[j] + bias;
    float gv = 0.5f * v * (1.f + erff(v * 0.70710678118f));
    c1[((size_t)b*HWp + (size_t)(by*8+py)*Ww + bx*8+px)*16 + co] = gv;
  }
}

// ------------------- K7: CAB conv2 3x3 16->64 + partial mean (LDS-staged weights) -------------------
__global__ __launch_bounds__(256) void k_conv2(
    const float* __restrict__ c1, const float* __restrict__ w2, const float* __restrict__ bc2,
    float* __restrict__ c2, float* __restrict__ sums){
  __shared__ float xt[100][17];      // 6.8 KB
  __shared__ float w_s[9][16][64];   // [tap][ci][co] = 36.9 KB
  __shared__ float red[4][64];
  int b = blockIdx.x / WPB;
  int r = blockIdx.x % WPB;
  int by = r / NWX, bx = r % NWX;
  for (int idx = threadIdx.x; idx < 9216; idx += 256) {
    int co = idx & 63, ci = (idx >> 6) & 15, tap = idx >> 10;
    w_s[tap][ci][co] = w2[(co*16 + ci)*9 + tap];
  }
  for (int idx = threadIdx.x; idx < 1600; idx += 256) {
    int p = idx >> 4, ci = idx & 15;
    int gy = by*8 + p/10 - 1;
    int gx = bx*8 + p%10 - 1;
    float val = 0.f;
    if (gy >= 0 && gy < Hh && gx >= 0 && gx < Ww)
      val = c1[((size_t)b*HWp + (size_t)gy*Ww + gx)*16 + ci];
    xt[p][ci] = val;
  }
  __syncthreads();
  int co = threadIdx.x & 63;
  int pg = threadIdx.x >> 6;   // 0..3 -> pixels pg*16 .. pg*16+15
  float acc[16];
  #pragma unroll
  for (int j = 0; j < 16; j++) acc[j] = 0.f;
  #pragma unroll
  for (int tap = 0; tap < 9; tap++) {
    int ky = tap / 3, kx = tap % 3;
    #pragma unroll
    for (int ci = 0; ci < 16; ci++) {
      float wv = w_s[tap][ci][co];
      #pragma unroll
      for (int j = 0; j < 16; j++) {
        int pp = pg*16 + j;
        int py = pp >> 3, px = pp & 7;
        acc[j] += xt[(py+ky)*10 + px+kx][ci] * wv;
      }
    }
  }
  float bias = bc2[co];
  float lsum = 0.f;
  #pragma unroll
  for (int j = 0; j < 16; j++) {
    int pp = pg*16 + j;
    int py = pp >> 3, px = pp & 7;
    float v = acc[j] + bias;
    c2[((size_t)b*HWp + (size_t)(by*8+py)*Ww + bx*8+px)*64 + co] = v;
    lsum += v;
  }
  red[pg][co] = lsum;
  __syncthreads();
  if (threadIdx.x < 64) {
    float s = red[0][threadIdx.x] + red[1][threadIdx.x] + red[2][threadIdx.x] + red[3][threadIdx.x];
    atomicAdd(&sums[b*64 + threadIdx.x], s);
  }
}

// ------------------- K8: channel attention -------------------
__global__ void k_att(const float* __restrict__ sums,
                      const float* __restrict__ wd, const float* __restrict__ bd,
                      const float* __restrict__ wu, const float* __restrict__ bu,
                      float* __restrict__ att){
  int tid = threadIdx.x;            // 128 threads
  int b = tid >> 6, co = tid & 63;
  float inv = 1.f / (float)HWp;
  float hid[4];
  #pragma unroll
  for (int j = 0; j < 4; j++) {
    float acc = bd[j];
    for (int c = 0; c < 64; c++) acc += wd[j*64+c] * (sums[b*64+c] * inv);
    hid[j] = fmaxf(acc, 0.f);
  }
  float acc = bu[co];
  #pragma unroll
  for (int j = 0; j < 4; j++) acc += wu[co*4+j] * hid[j];
  att[tid] = 1.f / (1.f + __expf(-acc));
}

// ------------------- K9: final combine + NHWC -> NCHW -------------------
__global__ __launch_bounds__(256) void k_final(
    const float* __restrict__ x1, const float* __restrict__ c2,
    const float* __restrict__ skip2, const float* __restrict__ att,
    float* __restrict__ out){
  __shared__ float t[64][65];
  int b = blockIdx.x / WPB;
  int hw0 = (blockIdx.x % WPB) * 64;
  int lane = threadIdx.x & 63, grp = threadIdx.x >> 6;
  float sk = skip2[lane], at = att[b*64 + lane];
  #pragma unroll
  for (int r = 0; r < 64; r += 4) {
    int hwl = r + grp;
    size_t T = (size_t)b*HWp + hw0 + hwl;
    t[hwl][lane] = x1[T*64+lane]*sk + c2[T*64+lane]*at;
  }
  __syncthreads();
  float* ob = out + (size_t)b * Cch * HWp;
  #pragma unroll
  for (int r = 0; r < 64; r += 4) {
    int c = r + grp;
    ob[(size_t)c*HWp + hw0 + lane] = t[lane][c];
  }
}

extern "C" void kernel_launch(void* const* d_in, const int* in_sizes, int n_in,
                              void* d_out, int out_size, void* d_ws, size_t ws_size,
                              hipStream_t stream) {
  (void)in_sizes; (void)n_in; (void)out_size; (void)ws_size;
  const float* x      = (const float*)d_in[0];
  const float* ln1_g  = (const float*)d_in[1];
  const float* ln1_b  = (const float*)d_in[2];
  const float* in_w   = (const float*)d_in[3];
  const float* in_b   = (const float*)d_in[4];
  const float* conv_w = (const float*)d_in[5];
  const float* conv_b = (const float*)d_in[6];
  const float* xproj_w= (const float*)d_in[7];
  const float* dt_w   = (const float*)d_in[8];
  const float* dt_b   = (const float*)d_in[9];
  const float* A_log  = (const float*)d_in[10];
  const float* Dp     = (const float*)d_in[11];
  const float* out_w  = (const float*)d_in[12];
  const float* out_b  = (const float*)d_in[13];
  const float* skip1  = (const float*)d_in[14];
  const float* ln2_g  = (const float*)d_in[15];
  const float* ln2_b  = (const float*)d_in[16];
  const float* skip2  = (const float*)d_in[17];
  const float* cab_w1 = (const float*)d_in[18];
  const float* cab_b1 = (const float*)d_in[19];
  const float* cab_w2 = (const float*)d_in[20];
  const float* cab_b2 = (const float*)d_in[21];
  const float* ca_wd  = (const float*)d_in[22];
  const float* ca_bd  = (const float*)d_in[23];
  const float* ca_wu  = (const float*)d_in[24];
  const float* ca_bu  = (const float*)d_in[25];

  float* ws   = (float*)d_ws;
  float* xT   = ws;                        // [0, 4718592)
  float* xc   = ws + 4718592;              // [4718592, 14155776)  g in-place; c2 aliases later
  float* z    = ws + 14155776;             // [14155776, 23592960) x1/x2 alias later
  float* c1   = ws + 23592960;             // [23592960, ...) conv1 output
  float* sums = ws + 26247168;             // 128
  float* att  = ws + 26247296;             // 128
  float* x1   = ws + 14155776;             // alias over z (z dead after k_scanf)
  float* x2   = ws + 18874368;             // alias over z second half
  float* c2   = ws + 4718592;              // alias over xc/g (dead after k_out)

  hipMemsetAsync(sums, 0, 128*sizeof(float), stream);
  k_transpose<<<NW, 256, 0, stream>>>(x, xT);
  k_stage1<<<NW, 256, 0, stream>>>(xT, ln1_g, ln1_b, in_w, in_b, conv_w, conv_b, xc, z);
  k_scanf<<<NW, 512, 0, stream>>>(xc, z, xproj_w, dt_w, dt_b, A_log, Dp);
  k_out<<<NW, 256, 0, stream>>>(xT, xc, out_w, out_b, skip1, ln2_g, ln2_b, x1, x2);
  k_conv1<<<NW, 256, 0, stream>>>(x2, cab_w1, cab_b1, c1);
  k_conv2<<<NW, 256, 0, stream>>>(c1, cab_w2, cab_b2, c2, sums);
  k_att<<<1, 128, 0, stream>>>(sums, ca_wd, ca_bd, ca_wu, ca_bu, att);
  k_final<<<NW, 256, 0, stream>>>(x1, c2, skip2, att, (float*)d_out);
}

// Round 6
// 397.562 us; speedup vs baseline: 1.2651x; 1.0480x over previous
//
#include <hip/hip_runtime.h>
#include <hip/hip_bf16.h>
#include <math.h>

// Problem constants
#define Hh 192
#define Ww 192
#define HWp (Hh*Ww)          // 36864
#define Bb 2
#define Cch 64
#define DI 128
#define NWX 24               // windows per row
#define WPB 576              // windows per batch
#define NW  1152             // total windows
#define DS 16
#define SHIFT 4

// ------------------- K1: NCHW -> NHWC transpose -------------------
__global__ __launch_bounds__(256) void k_transpose(const float* __restrict__ x, float* __restrict__ xT){
  __shared__ float t[64][65];
  int b   = blockIdx.x / WPB;
  int hw0 = (blockIdx.x % WPB) * 64;
  int lane = threadIdx.x & 63, grp = threadIdx.x >> 6;
  const float* xb = x + (size_t)b * Cch * HWp;
  #pragma unroll
  for (int r = 0; r < 64; r += 4) {
    int c = r + grp;
    t[c][lane] = xb[(size_t)c * HWp + hw0 + lane];
  }
  __syncthreads();
  float* xo = xT + ((size_t)b * HWp + hw0) * 64;
  #pragma unroll
  for (int r = 0; r < 64; r += 4) {
    int hwl = r + grp;
    xo[(size_t)hwl * 64 + lane] = t[lane][hwl];
  }
}

// ------------------- K2: shift + LN1 + in_proj + mask + conv1d + silu -------------------
__global__ __launch_bounds__(256) void k_stage1(
    const float* __restrict__ xT, const float* __restrict__ g1, const float* __restrict__ b1,
    const float* __restrict__ in_w, const float* __restrict__ in_b,
    const float* __restrict__ conv_w, const float* __restrict__ conv_b,
    float* __restrict__ xc, float* __restrict__ Zb){
  __shared__ __align__(16) float xs[64][68];
  int n = blockIdx.x;
  int b = n / WPB, wi = n % WPB;
  int wy = wi / NWX, wx = wi % NWX;
  int tid = threadIdx.x;
  int l = tid >> 2, q = tid & 3;       // token l (0..63), quarter q
  int iy = l >> 3, ix = l & 7;
  int h = wy*8 + iy, w = wx*8 + ix;    // shifted-space coords
  int hs = h + SHIFT; if (hs >= Hh) hs -= Hh;
  int ws2 = w + SHIFT; if (ws2 >= Ww) ws2 -= Ww;
  const float* src = xT + ((size_t)b*HWp + (size_t)hs*Ww + ws2) * 64 + q*16;
  float v[16];
  float s1 = 0.f, s2 = 0.f;
  #pragma unroll
  for (int k = 0; k < 4; k++) {
    float4 f = *reinterpret_cast<const float4*>(src + k*4);
    v[k*4+0]=f.x; v[k*4+1]=f.y; v[k*4+2]=f.z; v[k*4+3]=f.w;
  }
  #pragma unroll
  for (int i = 0; i < 16; i++) { s1 += v[i]; s2 += v[i]*v[i]; }
  s1 += __shfl_xor(s1, 1); s2 += __shfl_xor(s2, 1);
  s1 += __shfl_xor(s1, 2); s2 += __shfl_xor(s2, 2);
  float mu = s1 * (1.f/64.f);
  float var = s2 * (1.f/64.f) - mu*mu;
  float rstd = rsqrtf(var + 1e-5f);
  #pragma unroll
  for (int i = 0; i < 16; i++) {
    int c = q*16 + i;
    xs[l][c] = (v[i]-mu)*rstd*g1[c] + b1[c];
  }
  __syncthreads();
  // GEMM: 64 tokens x (64 -> 256). thread owns output column o = tid.
  int o = tid;
  float bias = in_b[o];
  int dd = o & 127;
  float cw0 = conv_w[dd], cw1 = conv_w[128+dd], cw2 = conv_w[256+dd], cw3 = conv_w[384+dd];
  float cb = conv_b[dd];
  float p1 = 0.f, p2 = 0.f, p3 = 0.f;
  for (int lc = 0; lc < 64; lc += 8) {
    float acc[8] = {0.f,0.f,0.f,0.f,0.f,0.f,0.f,0.f};
    for (int c = 0; c < 64; c++) {
      float wv = in_w[c*256 + o];
      #pragma unroll
      for (int j = 0; j < 8; j++) acc[j] += xs[lc+j][c] * wv;
    }
    if (o < 128) {
      #pragma unroll
      for (int j = 0; j < 8; j++) {
        int l2 = lc + j;
        int hh = wy*8 + (l2>>3), ww2 = wx*8 + (l2&7);
        float m = (hh < Hh-SHIFT && ww2 < Ww-SHIFT) ? 1.f : 0.f;
        float xv = (acc[j] + bias) * m;      // masked x_in
        float pre = cw3*xv + cw2*p1 + cw1*p2 + cw0*p3 + cb;
        xc[((size_t)n*64 + l2)*128 + o] = pre / (1.f + __expf(-pre));  // silu
        p3 = p2; p2 = p1; p1 = xv;
      }
    } else {
      #pragma unroll
      for (int j = 0; j < 8; j++)
        Zb[((size_t)n*64 + lc + j)*128 + (o-128)] = acc[j] + bias;
    }
  }
}

// ------------------- K3: dbc = xc @ xproj_w  (per-window 64x128 @ 128x36) -------------------
__global__ __launch_bounds__(256) void k_dbc(
    const float* __restrict__ xc, const float* __restrict__ xproj_w,
    float* __restrict__ dbc){
  __shared__ __align__(16) float xs[64][132];
  __shared__ float ws[128][37];
  int n = blockIdx.x;
  const float4* src = reinterpret_cast<const float4*>(xc + (size_t)n*8192);
  #pragma unroll
  for (int k = 0; k < 8; k++) {
    int gi = threadIdx.x + k*256;
    int t = gi >> 5, d4 = gi & 31;
    *reinterpret_cast<float4*>(&xs[t][d4*4]) = src[gi];
  }
  for (int idx = threadIdx.x; idx < 4608; idx += 256) {
    int c = idx / 36, j = idx - c*36;
    ws[c][j] = xproj_w[idx];
  }
  __syncthreads();
  int t = threadIdx.x >> 2, jq = threadIdx.x & 3;
  float acc[9];
  #pragma unroll
  for (int u = 0; u < 9; u++) acc[u] = 0.f;
  for (int c = 0; c < 128; c++) {
    float xv = xs[t][c];
    #pragma unroll
    for (int u = 0; u < 9; u++) acc[u] += xv * ws[c][jq*9+u];
  }
  float* dst = dbc + ((size_t)n*64 + t)*36 + jq*9;
  #pragma unroll
  for (int u = 0; u < 9; u++) dst[u] = acc[u];
}

// ------------------- K4: dt + selective scan + gate (1 thread per channel, 16 states in regs) -----
// Exploits A_log[d][s] = log(s+1) => exp(dt*A_s) = w^(s+1), w = exp(-dt): 1 exp + 15 muls
// (verified per-thread at runtime; general-exp fallback branch kept for safety).
__global__ __launch_bounds__(128) void k_scan3(
    float* __restrict__ xc,           // in: xc ; out: g = (y + D*xc)*silu(z)
    const float* __restrict__ Zb, const float* __restrict__ dbc,
    const float* __restrict__ dt_w, const float* __restrict__ dt_b,
    const float* __restrict__ A_log, const float* __restrict__ Dp){
  __shared__ __align__(16) float db[64][40];
  int n = blockIdx.x;
  int d = threadIdx.x;  // 0..127
  // stage dbc tile (rows are 144B = 9 float4s)
  const float4* dsrc = reinterpret_cast<const float4*>(dbc + (size_t)n*2304);
  for (int idx = threadIdx.x; idx < 576; idx += 128) {
    int t = idx / 9, j4 = idx - t*9;
    *reinterpret_cast<float4*>(&db[t][j4*4]) = dsrc[idx];
  }
  float dtb  = dt_b[d];
  float dtw0 = dt_w[d], dtw1 = dt_w[128+d], dtw2 = dt_w[256+d], dtw3 = dt_w[384+d];
  float Dd = Dp[d];
  float a[16];
  bool pow_ok = true;
  #pragma unroll
  for (int s = 0; s < 16; s++) {
    a[s] = -__expf(A_log[d*16+s]);
    pow_ok = pow_ok && (__builtin_fabsf(a[s] + (float)(s+1)) < 1e-3f);
  }
  float h[16];
  #pragma unroll
  for (int s = 0; s < 16; s++) h[s] = 0.f;
  const float* Xn = xc + (size_t)n*8192;
  const float* Zn = Zb + (size_t)n*8192;
  float* Gn = xc + (size_t)n*8192;
  __syncthreads();
  if (pow_ok) {
    #pragma unroll 4
    for (int i = 0; i < 64; i++) {
      float4 dv = *reinterpret_cast<const float4*>(&db[i][0]);
      float pre = dtb + dv.x*dtw0 + dv.y*dtw1 + dv.z*dtw2 + dv.w*dtw3;
      float dtv = (pre > 15.f) ? pre : __logf(1.f + __expf(pre));
      float xcv = Xn[i*128 + d];
      float zv  = Zn[i*128 + d];
      float du  = dtv * xcv;
      // binary power tree: P[s] = w^(s+1), depth 4
      float P[16];
      P[0] = __expf(-dtv);
      #pragma unroll
      for (int s = 1; s < 16; s++) {
        int aa = (s-1) >> 1, bb = (s-1) - aa;
        P[s] = P[aa] * P[bb];
      }
      float4 B0 = *reinterpret_cast<const float4*>(&db[i][4]);
      float4 B1 = *reinterpret_cast<const float4*>(&db[i][8]);
      float4 B2 = *reinterpret_cast<const float4*>(&db[i][12]);
      float4 B3 = *reinterpret_cast<const float4*>(&db[i][16]);
      float4 C0 = *reinterpret_cast<const float4*>(&db[i][20]);
      float4 C1 = *reinterpret_cast<const float4*>(&db[i][24]);
      float4 C2 = *reinterpret_cast<const float4*>(&db[i][28]);
      float4 C3 = *reinterpret_cast<const float4*>(&db[i][32]);
      const float* Bp = (const float*)&B0;  // B0..B3 contiguous? not guaranteed; use per-quad
      float y = 0.f;
      #pragma unroll
      for (int s = 0; s < 16; s++) {
        float Bs = (s < 4) ? ((const float*)&B0)[s] : (s < 8) ? ((const float*)&B1)[s-4]
                 : (s < 12) ? ((const float*)&B2)[s-8] : ((const float*)&B3)[s-12];
        float Cs = (s < 4) ? ((const float*)&C0)[s] : (s < 8) ? ((const float*)&C1)[s-4]
                 : (s < 12) ? ((const float*)&C2)[s-8] : ((const float*)&C3)[s-12];
        h[s] = P[s]*h[s] + du*Bs;
        y += h[s]*Cs;
      }
      (void)Bp;
      float yv = y + Dd*xcv;
      Gn[i*128 + d] = yv * (zv / (1.f + __expf(-zv)));
    }
  } else {
    #pragma unroll 2
    for (int i = 0; i < 64; i++) {
      float4 dv = *reinterpret_cast<const float4*>(&db[i][0]);
      float pre = dtb + dv.x*dtw0 + dv.y*dtw1 + dv.z*dtw2 + dv.w*dtw3;
      float dtv = (pre > 15.f) ? pre : __logf(1.f + __expf(pre));
      float xcv = Xn[i*128 + d];
      float zv  = Zn[i*128 + d];
      float du  = dtv * xcv;
      float y = 0.f;
      #pragma unroll
      for (int s = 0; s < 16; s++) {
        float e = __expf(dtv * a[s]);
        h[s] = e*h[s] + du*db[i][4+s];
        y += h[s]*db[i][20+s];
      }
      float yv = y + Dd*xcv;
      Gn[i*128 + d] = yv * (zv / (1.f + __expf(-zv)));
    }
  }
}

// ------------------- K5: out_proj + window-reverse + skip1 + LN2 -------------------
__global__ __launch_bounds__(256) void k_out(
    const float* __restrict__ xT, const float* __restrict__ g,
    const float* __restrict__ out_w, const float* __restrict__ out_b,
    const float* __restrict__ skip1, const float* __restrict__ g2, const float* __restrict__ b2,
    float* __restrict__ x1, float* __restrict__ x2){
  __shared__ __align__(16) float gs[64][132];
  __shared__ float outs[64][65];
  int n = blockIdx.x;
  int b = n / WPB, wi = n % WPB;
  int wy = wi / NWX, wx = wi % NWX;
  const float4* src = reinterpret_cast<const float4*>(g + (size_t)n*8192);
  #pragma unroll
  for (int k = 0; k < 8; k++) {
    int gi = threadIdx.x + k*256;
    int t = gi >> 5, d4 = gi & 31;
    *reinterpret_cast<float4*>(&gs[t][d4*4]) = src[gi];
  }
  __syncthreads();
  int o = threadIdx.x & 63, tg = threadIdx.x >> 6;
  float acc[16];
  #pragma unroll
  for (int i = 0; i < 16; i++) acc[i] = 0.f;
  for (int c = 0; c < 128; c++) {
    float wv = out_w[c*64 + o];
    #pragma unroll
    for (int i = 0; i < 16; i++) acc[i] += gs[tg*16 + i][c] * wv;
  }
  float obv = out_b[o];
  #pragma unroll
  for (int i = 0; i < 16; i++) outs[tg*16 + i][o] = acc[i] + obv;
  __syncthreads();
  // LN per token (4 lanes per token, 16 ch each)
  int l = threadIdx.x >> 2, q = threadIdx.x & 3;
  int hh = wy*8 + (l>>3), ww2 = wx*8 + (l&7);
  size_t T = (size_t)b*HWp + (size_t)hh*Ww + ww2;
  float v[16];
  float s1 = 0.f, s2 = 0.f;
  #pragma unroll
  for (int i = 0; i < 16; i++) {
    int c = q*16 + i;
    float val = xT[T*64 + c] * skip1[c] + outs[l][c];
    v[i] = val; s1 += val; s2 += val*val;
  }
  s1 += __shfl_xor(s1, 1); s2 += __shfl_xor(s2, 1);
  s1 += __shfl_xor(s1, 2); s2 += __shfl_xor(s2, 2);
  float mu = s1*(1.f/64.f);
  float var = s2*(1.f/64.f) - mu*mu;
  float rstd = rsqrtf(var + 1e-5f);
  #pragma unroll
  for (int i = 0; i < 16; i++) {
    int c = q*16 + i;
    x1[T*64 + c] = v[i];
    x2[T*64 + c] = (v[i]-mu)*rstd*g2[c] + b2[c];
  }
}

// ------------------- K6: CAB conv1 3x3 64->16 + gelu (LDS-staged weights) -------------------
__global__ __launch_bounds__(256) void k_conv1(
    const float* __restrict__ x2, const float* __restrict__ w1, const float* __restrict__ bc1,
    float* __restrict__ c1){
  __shared__ float xt[100][68];      // 10x10 pixels x 64 ch (pad 68) = 27.2 KB
  __shared__ float w_s[9][64][16];   // [tap][ci][co] = 36.9 KB
  int b = blockIdx.x / WPB;
  int r = blockIdx.x % WPB;
  int by = r / NWX, bx = r % NWX;
  for (int idx = threadIdx.x; idx < 9216; idx += 256) {
    int co = idx & 15, ci = (idx >> 4) & 63, tap = idx >> 10;
    w_s[tap][ci][co] = w1[(co*64 + ci)*9 + tap];
  }
  int lane = threadIdx.x & 63, grp = threadIdx.x >> 6;
  for (int p = grp; p < 100; p += 4) {
    int gy = by*8 + p/10 - 1;
    int gx = bx*8 + p%10 - 1;
    float val = 0.f;
    if (gy >= 0 && gy < Hh && gx >= 0 && gx < Ww)
      val = x2[((size_t)b*HWp + (size_t)gy*Ww + gx)*64 + lane];
    xt[p][lane] = val;
  }
  __syncthreads();
  int co = threadIdx.x & 15;
  int pp = threadIdx.x >> 4;   // 0..15
  int px = pp & 7, py0 = pp >> 3;
  float acc[4] = {0.f,0.f,0.f,0.f};
  #pragma unroll
  for (int tap = 0; tap < 9; tap++) {
    int ky = tap / 3, kx = tap % 3;
    const float* x0  = &xt[(py0+0+ky)*10 + px+kx][0];
    const float* x1p = &xt[(py0+2+ky)*10 + px+kx][0];
    const float* x2p = &xt[(py0+4+ky)*10 + px+kx][0];
    const float* x3p = &xt[(py0+6+ky)*10 + px+kx][0];
    #pragma unroll 4
    for (int ci = 0; ci < 64; ci++) {
      float wv = w_s[tap][ci][co];
      acc[0] += x0[ci]  * wv;
      acc[1] += x1p[ci] * wv;
      acc[2] += x2p[ci] * wv;
      acc[3] += x3p[ci] * wv;
    }
  }
  float bias = bc1[co];
  #pragma unroll
  for (int j = 0; j < 4; j++) {
    int py = py0 + 2*j;
    float v = acc[j] + bias;
    float gv = 0.5f * v * (1.f + erff(v * 0.70710678118f));
    c1[((size_t)b*HWp + (size_t)(by*8+py)*Ww + bx*8+px)*16 + co] = gv;
  }
}

// ------------------- K7: CAB conv2 3x3 16->64 + partial mean (LDS-staged weights) -------------------
__global__ __launch_bounds__(256) void k_conv2(
    const float* __restrict__ c1, const float* __restrict__ w2, const float* __restrict__ bc2,
    float* __restrict__ c2, float* __restrict__ sums){
  __shared__ float xt[100][17];      // 6.8 KB
  __shared__ float w_s[9][16][64];   // [tap][ci][co] = 36.9 KB
  __shared__ float red[4][64];
  int b = blockIdx.x / WPB;
  int r = blockIdx.x % WPB;
  int by = r / NWX, bx = r % NWX;
  for (int idx = threadIdx.x; idx < 9216; idx += 256) {
    int co = idx & 63, ci = (idx >> 6) & 15, tap = idx >> 10;
    w_s[tap][ci][co] = w2[(co*16 + ci)*9 + tap];
  }
  for (int idx = threadIdx.x; idx < 1600; idx += 256) {
    int p = idx >> 4, ci = idx & 15;
    int gy = by*8 + p/10 - 1;
    int gx = bx*8 + p%10 - 1;
    float val = 0.f;
    if (gy >= 0 && gy < Hh && gx >= 0 && gx < Ww)
      val = c1[((size_t)b*HWp + (size_t)gy*Ww + gx)*16 + ci];
    xt[p][ci] = val;
  }
  __syncthreads();
  int co = threadIdx.x & 63;
  int pg = threadIdx.x >> 6;   // 0..3 -> pixels pg*16 .. pg*16+15
  float acc[16];
  #pragma unroll
  for (int j = 0; j < 16; j++) acc[j] = 0.f;
  #pragma unroll
  for (int tap = 0; tap < 9; tap++) {
    int ky = tap / 3, kx = tap % 3;
    #pragma unroll
    for (int ci = 0; ci < 16; ci++) {
      float wv = w_s[tap][ci][co];
      #pragma unroll
      for (int j = 0; j < 16; j++) {
        int pp = pg*16 + j;
        int py = pp >> 3, px = pp & 7;
        acc[j] += xt[(py+ky)*10 + px+kx][ci] * wv;
      }
    }
  }
  float bias = bc2[co];
  float lsum = 0.f;
  #pragma unroll
  for (int j = 0; j < 16; j++) {
    int pp = pg*16 + j;
    int py = pp >> 3, px = pp & 7;
    float v = acc[j] + bias;
    c2[((size_t)b*HWp + (size_t)(by*8+py)*Ww + bx*8+px)*64 + co] = v;
    lsum += v;
  }
  red[pg][co] = lsum;
  __syncthreads();
  if (threadIdx.x < 64) {
    float s = red[0][threadIdx.x] + red[1][threadIdx.x] + red[2][threadIdx.x] + red[3][threadIdx.x];
    atomicAdd(&sums[b*64 + threadIdx.x], s);
  }
}

// ------------------- K8: channel attention -------------------
__global__ void k_att(const float* __restrict__ sums,
                      const float* __restrict__ wd, const float* __restrict__ bd,
                      const float* __restrict__ wu, const float* __restrict__ bu,
                      float* __restrict__ att){
  int tid = threadIdx.x;            // 128 threads
  int b = tid >> 6, co = tid & 63;
  float inv = 1.f / (float)HWp;
  float hid[4];
  #pragma unroll
  for (int j = 0; j < 4; j++) {
    float acc = bd[j];
    for (int c = 0; c < 64; c++) acc += wd[j*64+c] * (sums[b*64+c] * inv);
    hid[j] = fmaxf(acc, 0.f);
  }
  float acc = bu[co];
  #pragma unroll
  for (int j = 0; j < 4; j++) acc += wu[co*4+j] * hid[j];
  att[tid] = 1.f / (1.f + __expf(-acc));
}

// ------------------- K9: final combine + NHWC -> NCHW -------------------
__global__ __launch_bounds__(256) void k_final(
    const float* __restrict__ x1, const float* __restrict__ c2,
    const float* __restrict__ skip2, const float* __restrict__ att,
    float* __restrict__ out){
  __shared__ float t[64][65];
  int b = blockIdx.x / WPB;
  int hw0 = (blockIdx.x % WPB) * 64;
  int lane = threadIdx.x & 63, grp = threadIdx.x >> 6;
  float sk = skip2[lane], at = att[b*64 + lane];
  #pragma unroll
  for (int r = 0; r < 64; r += 4) {
    int hwl = r + grp;
    size_t T = (size_t)b*HWp + hw0 + hwl;
    t[hwl][lane] = x1[T*64+lane]*sk + c2[T*64+lane]*at;
  }
  __syncthreads();
  float* ob = out + (size_t)b * Cch * HWp;
  #pragma unroll
  for (int r = 0; r < 64; r += 4) {
    int c = r + grp;
    ob[(size_t)c*HWp + hw0 + lane] = t[lane][c];
  }
}

extern "C" void kernel_launch(void* const* d_in, const int* in_sizes, int n_in,
                              void* d_out, int out_size, void* d_ws, size_t ws_size,
                              hipStream_t stream) {
  (void)in_sizes; (void)n_in; (void)out_size; (void)ws_size;
  const float* x      = (const float*)d_in[0];
  const float* ln1_g  = (const float*)d_in[1];
  const float* ln1_b  = (const float*)d_in[2];
  const float* in_w   = (const float*)d_in[3];
  const float* in_b   = (const float*)d_in[4];
  const float* conv_w = (const float*)d_in[5];
  const float* conv_b = (const float*)d_in[6];
  const float* xproj_w= (const float*)d_in[7];
  const float* dt_w   = (const float*)d_in[8];
  const float* dt_b   = (const float*)d_in[9];
  const float* A_log  = (const float*)d_in[10];
  const float* Dp     = (const float*)d_in[11];
  const float* out_w  = (const float*)d_in[12];
  const float* out_b  = (const float*)d_in[13];
  const float* skip1  = (const float*)d_in[14];
  const float* ln2_g  = (const float*)d_in[15];
  const float* ln2_b  = (const float*)d_in[16];
  const float* skip2  = (const float*)d_in[17];
  const float* cab_w1 = (const float*)d_in[18];
  const float* cab_b1 = (const float*)d_in[19];
  const float* cab_w2 = (const float*)d_in[20];
  const float* cab_b2 = (const float*)d_in[21];
  const float* ca_wd  = (const float*)d_in[22];
  const float* ca_bd  = (const float*)d_in[23];
  const float* ca_wu  = (const float*)d_in[24];
  const float* ca_bu  = (const float*)d_in[25];

  float* ws   = (float*)d_ws;
  float* xT   = ws;                        // [0, 4718592)
  float* xc   = ws + 4718592;              // [4718592, 14155776)  g in-place; c2 aliases later
  float* z    = ws + 14155776;             // [14155776, 23592960) x1/x2 alias later
  float* dbc  = ws + 23592960;             // [23592960, 26247168) c1 aliases later
  float* sums = ws + 26247168;             // 128
  float* att  = ws + 26247296;             // 128
  float* x1   = ws + 14155776;             // alias over z (z dead after k_scan3)
  float* x2   = ws + 18874368;             // alias over z second half
  float* c1   = ws + 23592960;             // alias over dbc (dead after k_scan3)
  float* c2   = ws + 4718592;              // alias over xc/g (dead after k_out)

  hipMemsetAsync(sums, 0, 128*sizeof(float), stream);
  k_transpose<<<NW, 256, 0, stream>>>(x, xT);
  k_stage1<<<NW, 256, 0, stream>>>(xT, ln1_g, ln1_b, in_w, in_b, conv_w, conv_b, xc, z);
  k_dbc<<<NW, 256, 0, stream>>>(xc, xproj_w, dbc);
  k_scan3<<<NW, 128, 0, stream>>>(xc, z, dbc, dt_w, dt_b, A_log, Dp);
  k_out<<<NW, 256, 0, stream>>>(xT, xc, out_w, out_b, skip1, ln2_g, ln2_b, x1, x2);
  k_conv1<<<NW, 256, 0, stream>>>(x2, cab_w1, cab_b1, c1);
  k_conv2<<<NW, 256, 0, stream>>>(c1, cab_w2, cab_b2, c2, sums);
  k_att<<<1, 128, 0, stream>>>(sums, ca_wd, ca_bd, ca_wu, ca_bu, att);
  k_final<<<NW, 256, 0, stream>>>(x1, c2, skip2, att, (float*)d_out);
}

// Round 7
// 275.970 us; speedup vs baseline: 1.8225x; 1.4406x over previous
//
#include <hip/hip_runtime.h>
#include <hip/hip_bf16.h>
#include <math.h>

// Problem constants
#define Hh 192
#define Ww 192
#define HWp (Hh*Ww)          // 36864
#define Bb 2
#define Cch 64
#define DI 128
#define NWX 24               // windows per row
#define WPB 576              // windows per batch
#define NW  1152             // total windows
#define DS 16
#define SHIFT 4

typedef __attribute__((ext_vector_type(8))) short short8v;  // 8 bf16 (4 VGPRs)
typedef __attribute__((ext_vector_type(4))) float f32x4;    // MFMA accumulator

// ------------------- K1: NCHW -> NHWC transpose -------------------
__global__ __launch_bounds__(256) void k_transpose(const float* __restrict__ x, float* __restrict__ xT){
  __shared__ float t[64][65];
  int b   = blockIdx.x / WPB;
  int hw0 = (blockIdx.x % WPB) * 64;
  int lane = threadIdx.x & 63, grp = threadIdx.x >> 6;
  const float* xb = x + (size_t)b * Cch * HWp;
  #pragma unroll
  for (int r = 0; r < 64; r += 4) {
    int c = r + grp;
    t[c][lane] = xb[(size_t)c * HWp + hw0 + lane];
  }
  __syncthreads();
  float* xo = xT + ((size_t)b * HWp + hw0) * 64;
  #pragma unroll
  for (int r = 0; r < 64; r += 4) {
    int hwl = r + grp;
    xo[(size_t)hwl * 64 + lane] = t[lane][hwl];
  }
}

// ------------------- K2: shift + LN1 + in_proj + mask + conv1d + silu -------------------
__global__ __launch_bounds__(256) void k_stage1(
    const float* __restrict__ xT, const float* __restrict__ g1, const float* __restrict__ b1,
    const float* __restrict__ in_w, const float* __restrict__ in_b,
    const float* __restrict__ conv_w, const float* __restrict__ conv_b,
    float* __restrict__ xc, float* __restrict__ Zb){
  __shared__ __align__(16) float xs[64][68];
  int n = blockIdx.x;
  int b = n / WPB, wi = n % WPB;
  int wy = wi / NWX, wx = wi % NWX;
  int tid = threadIdx.x;
  int l = tid >> 2, q = tid & 3;       // token l (0..63), quarter q
  int iy = l >> 3, ix = l & 7;
  int h = wy*8 + iy, w = wx*8 + ix;    // shifted-space coords
  int hs = h + SHIFT; if (hs >= Hh) hs -= Hh;
  int ws2 = w + SHIFT; if (ws2 >= Ww) ws2 -= Ww;
  const float* src = xT + ((size_t)b*HWp + (size_t)hs*Ww + ws2) * 64 + q*16;
  float v[16];
  float s1 = 0.f, s2 = 0.f;
  #pragma unroll
  for (int k = 0; k < 4; k++) {
    float4 f = *reinterpret_cast<const float4*>(src + k*4);
    v[k*4+0]=f.x; v[k*4+1]=f.y; v[k*4+2]=f.z; v[k*4+3]=f.w;
  }
  #pragma unroll
  for (int i = 0; i < 16; i++) { s1 += v[i]; s2 += v[i]*v[i]; }
  s1 += __shfl_xor(s1, 1); s2 += __shfl_xor(s2, 1);
  s1 += __shfl_xor(s1, 2); s2 += __shfl_xor(s2, 2);
  float mu = s1 * (1.f/64.f);
  float var = s2 * (1.f/64.f) - mu*mu;
  float rstd = rsqrtf(var + 1e-5f);
  #pragma unroll
  for (int i = 0; i < 16; i++) {
    int c = q*16 + i;
    xs[l][c] = (v[i]-mu)*rstd*g1[c] + b1[c];
  }
  __syncthreads();
  // GEMM: 64 tokens x (64 -> 256). thread owns output column o = tid.
  int o = tid;
  float bias = in_b[o];
  int dd = o & 127;
  float cw0 = conv_w[dd], cw1 = conv_w[128+dd], cw2 = conv_w[256+dd], cw3 = conv_w[384+dd];
  float cb = conv_b[dd];
  float p1 = 0.f, p2 = 0.f, p3 = 0.f;
  for (int lc = 0; lc < 64; lc += 8) {
    float acc[8] = {0.f,0.f,0.f,0.f,0.f,0.f,0.f,0.f};
    for (int c = 0; c < 64; c++) {
      float wv = in_w[c*256 + o];
      #pragma unroll
      for (int j = 0; j < 8; j++) acc[j] += xs[lc+j][c] * wv;
    }
    if (o < 128) {
      #pragma unroll
      for (int j = 0; j < 8; j++) {
        int l2 = lc + j;
        int hh = wy*8 + (l2>>3), ww2 = wx*8 + (l2&7);
        float m = (hh < Hh-SHIFT && ww2 < Ww-SHIFT) ? 1.f : 0.f;
        float xv = (acc[j] + bias) * m;      // masked x_in
        float pre = cw3*xv + cw2*p1 + cw1*p2 + cw0*p3 + cb;
        xc[((size_t)n*64 + l2)*128 + o] = pre / (1.f + __expf(-pre));  // silu
        p3 = p2; p2 = p1; p1 = xv;
      }
    } else {
      #pragma unroll
      for (int j = 0; j < 8; j++)
        Zb[((size_t)n*64 + lc + j)*128 + (o-128)] = acc[j] + bias;
    }
  }
}

// ------------------- K3: dbc = xc @ xproj_w  (per-window 64x128 @ 128x36) -------------------
__global__ __launch_bounds__(256) void k_dbc(
    const float* __restrict__ xc, const float* __restrict__ xproj_w,
    float* __restrict__ dbc){
  __shared__ __align__(16) float xs[64][132];
  __shared__ float ws[128][37];
  int n = blockIdx.x;
  const float4* src = reinterpret_cast<const float4*>(xc + (size_t)n*8192);
  #pragma unroll
  for (int k = 0; k < 8; k++) {
    int gi = threadIdx.x + k*256;
    int t = gi >> 5, d4 = gi & 31;
    *reinterpret_cast<float4*>(&xs[t][d4*4]) = src[gi];
  }
  for (int idx = threadIdx.x; idx < 4608; idx += 256) {
    int c = idx / 36, j = idx - c*36;
    ws[c][j] = xproj_w[idx];
  }
  __syncthreads();
  int t = threadIdx.x >> 2, jq = threadIdx.x & 3;
  float acc[9];
  #pragma unroll
  for (int u = 0; u < 9; u++) acc[u] = 0.f;
  for (int c = 0; c < 128; c++) {
    float xv = xs[t][c];
    #pragma unroll
    for (int u = 0; u < 9; u++) acc[u] += xv * ws[c][jq*9+u];
  }
  float* dst = dbc + ((size_t)n*64 + t)*36 + jq*9;
  #pragma unroll
  for (int u = 0; u < 9; u++) dst[u] = acc[u];
}

// ------------------- K4: dt + selective scan + gate (1 thread per channel, 16 states in regs) -----
__global__ __launch_bounds__(128) void k_scan3(
    float* __restrict__ xc,           // in: xc ; out: g = (y + D*xc)*silu(z)
    const float* __restrict__ Zb, const float* __restrict__ dbc,
    const float* __restrict__ dt_w, const float* __restrict__ dt_b,
    const float* __restrict__ A_log, const float* __restrict__ Dp){
  __shared__ __align__(16) float db[64][40];
  int n = blockIdx.x;
  int d = threadIdx.x;  // 0..127
  const float4* dsrc = reinterpret_cast<const float4*>(dbc + (size_t)n*2304);
  for (int idx = threadIdx.x; idx < 576; idx += 128) {
    int t = idx / 9, j4 = idx - t*9;
    *reinterpret_cast<float4*>(&db[t][j4*4]) = dsrc[idx];
  }
  float dtb  = dt_b[d];
  float dtw0 = dt_w[d], dtw1 = dt_w[128+d], dtw2 = dt_w[256+d], dtw3 = dt_w[384+d];
  float Dd = Dp[d];
  float a[16];
  bool pow_ok = true;
  #pragma unroll
  for (int s = 0; s < 16; s++) {
    a[s] = -__expf(A_log[d*16+s]);
    pow_ok = pow_ok && (__builtin_fabsf(a[s] + (float)(s+1)) < 1e-3f);
  }
  float h[16];
  #pragma unroll
  for (int s = 0; s < 16; s++) h[s] = 0.f;
  const float* Xn = xc + (size_t)n*8192;
  const float* Zn = Zb + (size_t)n*8192;
  float* Gn = xc + (size_t)n*8192;
  __syncthreads();
  if (pow_ok) {
    #pragma unroll 4
    for (int i = 0; i < 64; i++) {
      float4 dv = *reinterpret_cast<const float4*>(&db[i][0]);
      float pre = dtb + dv.x*dtw0 + dv.y*dtw1 + dv.z*dtw2 + dv.w*dtw3;
      float dtv = (pre > 15.f) ? pre : __logf(1.f + __expf(pre));
      float xcv = Xn[i*128 + d];
      float zv  = Zn[i*128 + d];
      float du  = dtv * xcv;
      float P[16];
      P[0] = __expf(-dtv);
      #pragma unroll
      for (int s = 1; s < 16; s++) {
        int aa = (s-1) >> 1, bb = (s-1) - aa;
        P[s] = P[aa] * P[bb];
      }
      float4 B0 = *reinterpret_cast<const float4*>(&db[i][4]);
      float4 B1 = *reinterpret_cast<const float4*>(&db[i][8]);
      float4 B2 = *reinterpret_cast<const float4*>(&db[i][12]);
      float4 B3 = *reinterpret_cast<const float4*>(&db[i][16]);
      float4 C0 = *reinterpret_cast<const float4*>(&db[i][20]);
      float4 C1 = *reinterpret_cast<const float4*>(&db[i][24]);
      float4 C2 = *reinterpret_cast<const float4*>(&db[i][28]);
      float4 C3 = *reinterpret_cast<const float4*>(&db[i][32]);
      float y = 0.f;
      #pragma unroll
      for (int s = 0; s < 16; s++) {
        float Bs = (s < 4) ? ((const float*)&B0)[s] : (s < 8) ? ((const float*)&B1)[s-4]
                 : (s < 12) ? ((const float*)&B2)[s-8] : ((const float*)&B3)[s-12];
        float Cs = (s < 4) ? ((const float*)&C0)[s] : (s < 8) ? ((const float*)&C1)[s-4]
                 : (s < 12) ? ((const float*)&C2)[s-8] : ((const float*)&C3)[s-12];
        h[s] = P[s]*h[s] + du*Bs;
        y += h[s]*Cs;
      }
      float yv = y + Dd*xcv;
      Gn[i*128 + d] = yv * (zv / (1.f + __expf(-zv)));
    }
  } else {
    #pragma unroll 2
    for (int i = 0; i < 64; i++) {
      float4 dv = *reinterpret_cast<const float4*>(&db[i][0]);
      float pre = dtb + dv.x*dtw0 + dv.y*dtw1 + dv.z*dtw2 + dv.w*dtw3;
      float dtv = (pre > 15.f) ? pre : __logf(1.f + __expf(pre));
      float xcv = Xn[i*128 + d];
      float zv  = Zn[i*128 + d];
      float du  = dtv * xcv;
      float y = 0.f;
      #pragma unroll
      for (int s = 0; s < 16; s++) {
        float e = __expf(dtv * a[s]);
        h[s] = e*h[s] + du*db[i][4+s];
        y += h[s]*db[i][20+s];
      }
      float yv = y + Dd*xcv;
      Gn[i*128 + d] = yv * (zv / (1.f + __expf(-zv)));
    }
  }
}

// ------------------- K5: out_proj + window-reverse + skip1 + LN2 -------------------
__global__ __launch_bounds__(256) void k_out(
    const float* __restrict__ xT, const float* __restrict__ g,
    const float* __restrict__ out_w, const float* __restrict__ out_b,
    const float* __restrict__ skip1, const float* __restrict__ g2, const float* __restrict__ b2,
    float* __restrict__ x1, float* __restrict__ x2){
  __shared__ __align__(16) float gs[64][132];
  __shared__ float outs[64][65];
  int n = blockIdx.x;
  int b = n / WPB, wi = n % WPB;
  int wy = wi / NWX, wx = wi % NWX;
  const float4* src = reinterpret_cast<const float4*>(g + (size_t)n*8192);
  #pragma unroll
  for (int k = 0; k < 8; k++) {
    int gi = threadIdx.x + k*256;
    int t = gi >> 5, d4 = gi & 31;
    *reinterpret_cast<float4*>(&gs[t][d4*4]) = src[gi];
  }
  __syncthreads();
  int o = threadIdx.x & 63, tg = threadIdx.x >> 6;
  float acc[16];
  #pragma unroll
  for (int i = 0; i < 16; i++) acc[i] = 0.f;
  for (int c = 0; c < 128; c++) {
    float wv = out_w[c*64 + o];
    #pragma unroll
    for (int i = 0; i < 16; i++) acc[i] += gs[tg*16 + i][c] * wv;
  }
  float obv = out_b[o];
  #pragma unroll
  for (int i = 0; i < 16; i++) outs[tg*16 + i][o] = acc[i] + obv;
  __syncthreads();
  int l = threadIdx.x >> 2, q = threadIdx.x & 3;
  int hh = wy*8 + (l>>3), ww2 = wx*8 + (l&7);
  size_t T = (size_t)b*HWp + (size_t)hh*Ww + ww2;
  float v[16];
  float s1 = 0.f, s2 = 0.f;
  #pragma unroll
  for (int i = 0; i < 16; i++) {
    int c = q*16 + i;
    float val = xT[T*64 + c] * skip1[c] + outs[l][c];
    v[i] = val; s1 += val; s2 += val*val;
  }
  s1 += __shfl_xor(s1, 1); s2 += __shfl_xor(s2, 1);
  s1 += __shfl_xor(s1, 2); s2 += __shfl_xor(s2, 2);
  float mu = s1*(1.f/64.f);
  float var = s2*(1.f/64.f) - mu*mu;
  float rstd = rsqrtf(var + 1e-5f);
  #pragma unroll
  for (int i = 0; i < 16; i++) {
    int c = q*16 + i;
    x1[T*64 + c] = v[i];
    x2[T*64 + c] = (v[i]-mu)*rstd*g2[c] + b2[c];
  }
}

// ------------------- K6: CAB conv1 3x3 64->16 + gelu (bf16 MFMA implicit GEMM) -------------------
// Per block: one 8x8 tile. 4 waves x one 16x16x32 MFMA C-tile (16 pixels x 16 co).
// A: patches [pix][ci] from xt (bf16); B: weights [tap][co][ci] (bf16, = B^T layout, contiguous K).
__global__ __launch_bounds__(256) void k_conv1(
    const float* __restrict__ x2, const float* __restrict__ w1, const float* __restrict__ bc1,
    __hip_bfloat16* __restrict__ c1){
  __shared__ __align__(16) __hip_bfloat16 xt[100][72];   // 14.4 KB (row 144B, 16B-aligned)
  __shared__ __align__(16) __hip_bfloat16 wt[9][16][64]; // 18.4 KB [tap][co][ci]
  int b = blockIdx.x / WPB;
  int r = blockIdx.x % WPB;
  int by = r / NWX, bx = r % NWX;
  // stage weights: w1 linear = co*576 + ci*9 + tap
  for (int idx = threadIdx.x; idx < 9216; idx += 256) {
    int co = idx / 576, rest = idx % 576;
    int ci = rest / 9, tap = rest % 9;
    wt[tap][co][ci] = (__hip_bfloat16)w1[idx];
  }
  // stage 10x10x64 input tile as bf16
  for (int idx = threadIdx.x; idx < 1600; idx += 256) {
    int p = idx >> 4, c4 = idx & 15;
    int gy = by*8 + p/10 - 1;
    int gx = bx*8 + p%10 - 1;
    float4 v = make_float4(0.f,0.f,0.f,0.f);
    if (gy >= 0 && gy < Hh && gx >= 0 && gx < Ww)
      v = *reinterpret_cast<const float4*>(&x2[((size_t)b*HWp + (size_t)gy*Ww + gx)*64 + c4*4]);
    __hip_bfloat16 tmp[4] = {(__hip_bfloat16)v.x,(__hip_bfloat16)v.y,(__hip_bfloat16)v.z,(__hip_bfloat16)v.w};
    *reinterpret_cast<ushort4*>(&xt[p][c4*4]) = *reinterpret_cast<ushort4*>(tmp);
  }
  __syncthreads();
  int wv = threadIdx.x >> 6;     // wave 0..3 -> 16-pixel group
  int l  = threadIdx.x & 63;
  int col = l & 15, g = l >> 4;  // col: A-row pixel & B/C col (co); g: k-subgroup
  int apix = wv*16 + col;
  int apy = apix >> 3, apx = apix & 7;
  f32x4 acc = {0.f,0.f,0.f,0.f};
  #pragma unroll
  for (int tap = 0; tap < 9; tap++) {
    int ky = tap/3, kx = tap%3;
    const __hip_bfloat16* arow = &xt[(apy+ky)*10 + apx+kx][0];
    #pragma unroll
    for (int kh = 0; kh < 2; kh++) {
      short8v af = *reinterpret_cast<const short8v*>(&arow[kh*32 + g*8]);
      short8v bf = *reinterpret_cast<const short8v*>(&wt[tap][col][kh*32 + g*8]);
      acc = __builtin_amdgcn_mfma_f32_16x16x32_bf16(af, bf, acc, 0, 0, 0);
    }
  }
  float bias = bc1[col];
  #pragma unroll
  for (int j = 0; j < 4; j++) {
    int opix = wv*16 + g*4 + j;
    int oy = by*8 + (opix>>3), ox = bx*8 + (opix&7);
    float v = acc[j] + bias;
    float gv = 0.5f * v * (1.f + erff(v * 0.70710678118f));
    c1[((size_t)b*HWp + (size_t)oy*Ww + ox)*16 + col] = (__hip_bfloat16)gv;
  }
}

// ------------------- K7: CAB conv2 3x3 16->64 + partial mean (bf16 MFMA implicit GEMM) ------------
// K=144 -> 5 tap-pairs of K=32 (tap 9 zero-padded). 4 waves x 16 pixels x 4 co-tiles.
__global__ __launch_bounds__(256) void k_conv2(
    const __hip_bfloat16* __restrict__ c1, const float* __restrict__ w2, const float* __restrict__ bc2,
    float* __restrict__ c2, float* __restrict__ sums){
  __shared__ __align__(16) __hip_bfloat16 xt[100][16];   // 3.2 KB (row 32B)
  __shared__ __align__(16) __hip_bfloat16 wt[5][64][32]; // 20.5 KB [pair][co][k]
  __shared__ float red[4][64];
  int b = blockIdx.x / WPB;
  int r = blockIdx.x % WPB;
  int by = r / NWX, bx = r % NWX;
  // stage weights: w2 linear = co*144 + ci*9 + tap ; pair p covers taps 2p,2p+1 (tap 9 -> 0)
  for (int idx = threadIdx.x; idx < 10240; idx += 256) {
    int k = idx & 31, co = (idx >> 5) & 63, p = idx >> 11;
    int tap = p*2 + (k >> 4);
    int ci = k & 15;
    float wv = (tap < 9) ? w2[co*144 + ci*9 + tap] : 0.f;
    wt[p][co][k] = (__hip_bfloat16)wv;
  }
  // stage 10x10x16 bf16 tile
  for (int idx = threadIdx.x; idx < 400; idx += 256) {
    int p = idx >> 2, c4 = idx & 3;
    int gy = by*8 + p/10 - 1;
    int gx = bx*8 + p%10 - 1;
    ushort4 v = {0,0,0,0};
    if (gy >= 0 && gy < Hh && gx >= 0 && gx < Ww)
      v = *reinterpret_cast<const ushort4*>(&c1[((size_t)b*HWp + (size_t)gy*Ww + gx)*16 + c4*4]);
    *reinterpret_cast<ushort4*>(&xt[p][c4*4]) = v;
  }
  __syncthreads();
  int wv4 = threadIdx.x >> 6;
  int l   = threadIdx.x & 63;
  int col = l & 15, g = l >> 4;
  int apix = wv4*16 + col;
  int apy = apix >> 3, apx = apix & 7;
  f32x4 acc[4] = {{0.f,0.f,0.f,0.f},{0.f,0.f,0.f,0.f},{0.f,0.f,0.f,0.f},{0.f,0.f,0.f,0.f}};
  #pragma unroll
  for (int p = 0; p < 5; p++) {
    int tap = p*2 + (g >> 1); if (tap > 8) tap = 8;   // fake tap 9 -> any valid row (weights=0)
    int ky = tap/3, kx = tap%3;
    short8v af = *reinterpret_cast<const short8v*>(&xt[(apy+ky)*10 + apx+kx][(g&1)*8]);
    #pragma unroll
    for (int ct = 0; ct < 4; ct++) {
      short8v bf = *reinterpret_cast<const short8v*>(&wt[p][ct*16 + col][g*8]);
      acc[ct] = __builtin_amdgcn_mfma_f32_16x16x32_bf16(af, bf, acc[ct], 0, 0, 0);
    }
  }
  #pragma unroll
  for (int ct = 0; ct < 4; ct++) {
    int co = ct*16 + col;
    float bias = bc2[co];
    float part = 0.f;
    #pragma unroll
    for (int j = 0; j < 4; j++) {
      int opix = wv4*16 + g*4 + j;
      int oy = by*8 + (opix>>3), ox = bx*8 + (opix&7);
      float v = acc[ct][j] + bias;
      c2[((size_t)b*HWp + (size_t)oy*Ww + ox)*64 + co] = v;
      part += v;
    }
    part += __shfl_xor(part, 16);
    part += __shfl_xor(part, 32);
    if (g == 0) red[wv4][co] = part;
  }
  __syncthreads();
  if (threadIdx.x < 64) {
    float s = red[0][threadIdx.x] + red[1][threadIdx.x] + red[2][threadIdx.x] + red[3][threadIdx.x];
    atomicAdd(&sums[b*64 + threadIdx.x], s);
  }
}

// ------------------- K8: channel attention -------------------
__global__ void k_att(const float* __restrict__ sums,
                      const float* __restrict__ wd, const float* __restrict__ bd,
                      const float* __restrict__ wu, const float* __restrict__ bu,
                      float* __restrict__ att){
  int tid = threadIdx.x;            // 128 threads
  int b = tid >> 6, co = tid & 63;
  float inv = 1.f / (float)HWp;
  float hid[4];
  #pragma unroll
  for (int j = 0; j < 4; j++) {
    float acc = bd[j];
    for (int c = 0; c < 64; c++) acc += wd[j*64+c] * (sums[b*64+c] * inv);
    hid[j] = fmaxf(acc, 0.f);
  }
  float acc = bu[co];
  #pragma unroll
  for (int j = 0; j < 4; j++) acc += wu[co*4+j] * hid[j];
  att[tid] = 1.f / (1.f + __expf(-acc));
}

// ------------------- K9: final combine + NHWC -> NCHW -------------------
__global__ __launch_bounds__(256) void k_final(
    const float* __restrict__ x1, const float* __restrict__ c2,
    const float* __restrict__ skip2, const float* __restrict__ att,
    float* __restrict__ out){
  __shared__ float t[64][65];
  int b = blockIdx.x / WPB;
  int hw0 = (blockIdx.x % WPB) * 64;
  int lane = threadIdx.x & 63, grp = threadIdx.x >> 6;
  float sk = skip2[lane], at = att[b*64 + lane];
  #pragma unroll
  for (int r = 0; r < 64; r += 4) {
    int hwl = r + grp;
    size_t T = (size_t)b*HWp + hw0 + hwl;
    t[hwl][lane] = x1[T*64+lane]*sk + c2[T*64+lane]*at;
  }
  __syncthreads();
  float* ob = out + (size_t)b * Cch * HWp;
  #pragma unroll
  for (int r = 0; r < 64; r += 4) {
    int c = r + grp;
    ob[(size_t)c*HWp + hw0 + lane] = t[lane][c];
  }
}

extern "C" void kernel_launch(void* const* d_in, const int* in_sizes, int n_in,
                              void* d_out, int out_size, void* d_ws, size_t ws_size,
                              hipStream_t stream) {
  (void)in_sizes; (void)n_in; (void)out_size; (void)ws_size;
  const float* x      = (const float*)d_in[0];
  const float* ln1_g  = (const float*)d_in[1];
  const float* ln1_b  = (const float*)d_in[2];
  const float* in_w   = (const float*)d_in[3];
  const float* in_b   = (const float*)d_in[4];
  const float* conv_w = (const float*)d_in[5];
  const float* conv_b = (const float*)d_in[6];
  const float* xproj_w= (const float*)d_in[7];
  const float* dt_w   = (const float*)d_in[8];
  const float* dt_b   = (const float*)d_in[9];
  const float* A_log  = (const float*)d_in[10];
  const float* Dp     = (const float*)d_in[11];
  const float* out_w  = (const float*)d_in[12];
  const float* out_b  = (const float*)d_in[13];
  const float* skip1  = (const float*)d_in[14];
  const float* ln2_g  = (const float*)d_in[15];
  const float* ln2_b  = (const float*)d_in[16];
  const float* skip2  = (const float*)d_in[17];
  const float* cab_w1 = (const float*)d_in[18];
  const float* cab_b1 = (const float*)d_in[19];
  const float* cab_w2 = (const float*)d_in[20];
  const float* cab_b2 = (const float*)d_in[21];
  const float* ca_wd  = (const float*)d_in[22];
  const float* ca_bd  = (const float*)d_in[23];
  const float* ca_wu  = (const float*)d_in[24];
  const float* ca_bu  = (const float*)d_in[25];

  float* ws   = (float*)d_ws;
  float* xT   = ws;                        // [0, 4718592)
  float* xc   = ws + 4718592;              // [4718592, 14155776)  g in-place; c2 aliases later
  float* z    = ws + 14155776;             // [14155776, 23592960) x1/x2 alias later
  float* dbc  = ws + 23592960;             // [23592960, 26247168) c1 aliases later
  float* sums = ws + 26247168;             // 128
  float* att  = ws + 26247296;             // 128
  float* x1   = ws + 14155776;             // alias over z (z dead after k_scan3)
  float* x2   = ws + 18874368;             // alias over z second half
  __hip_bfloat16* c1 = (__hip_bfloat16*)(ws + 23592960); // alias over dbc (dead after k_scan3)
  float* c2   = ws + 4718592;              // alias over xc/g (dead after k_out)

  hipMemsetAsync(sums, 0, 128*sizeof(float), stream);
  k_transpose<<<NW, 256, 0, stream>>>(x, xT);
  k_stage1<<<NW, 256, 0, stream>>>(xT, ln1_g, ln1_b, in_w, in_b, conv_w, conv_b, xc, z);
  k_dbc<<<NW, 256, 0, stream>>>(xc, xproj_w, dbc);
  k_scan3<<<NW, 128, 0, stream>>>(xc, z, dbc, dt_w, dt_b, A_log, Dp);
  k_out<<<NW, 256, 0, stream>>>(xT, xc, out_w, out_b, skip1, ln2_g, ln2_b, x1, x2);
  k_conv1<<<NW, 256, 0, stream>>>(x2, cab_w1, cab_b1, c1);
  k_conv2<<<NW, 256, 0, stream>>>(c1, cab_w2, cab_b2, c2, sums);
  k_att<<<1, 128, 0, stream>>>(sums, ca_wd, ca_bd, ca_wu, ca_bu, att);
  k_final<<<NW, 256, 0, stream>>>(x1, c2, skip2, att, (float*)d_out);
}

// Round 8
// 244.503 us; speedup vs baseline: 2.0570x; 1.1287x over previous
//
#include <hip/hip_runtime.h>
#include <hip/hip_bf16.h>
#include <math.h>

// Problem constants
#define Hh 192
#define Ww 192
#define HWp (Hh*Ww)          // 36864
#define Bb 2
#define Cch 64
#define DI 128
#define NWX 24               // windows per row
#define WPB 576              // windows per batch
#define NW  1152             // total windows
#define DS 16
#define SHIFT 4

typedef __attribute__((ext_vector_type(8))) short short8v;  // 8 bf16 (4 VGPRs)
typedef __attribute__((ext_vector_type(4))) float f32x4;    // MFMA accumulator

// ------------------- K1: NCHW -> NHWC transpose -------------------
__global__ __launch_bounds__(256) void k_transpose(const float* __restrict__ x, float* __restrict__ xT){
  __shared__ float t[64][65];
  int b   = blockIdx.x / WPB;
  int hw0 = (blockIdx.x % WPB) * 64;
  int lane = threadIdx.x & 63, grp = threadIdx.x >> 6;
  const float* xb = x + (size_t)b * Cch * HWp;
  #pragma unroll
  for (int r = 0; r < 64; r += 4) {
    int c = r + grp;
    t[c][lane] = xb[(size_t)c * HWp + hw0 + lane];
  }
  __syncthreads();
  float* xo = xT + ((size_t)b * HWp + hw0) * 64;
  #pragma unroll
  for (int r = 0; r < 64; r += 4) {
    int hwl = r + grp;
    xo[(size_t)hwl * 64 + lane] = t[lane][hwl];
  }
}

// ------------------- K2: shift + LN1 + in_proj(MFMA bf16) + mask + conv1d + silu -------------------
// Per window: xs[64tok][64ch] bf16, wt = in_w^T bf16. 4 waves x (4 M x 4 N x 2 K) MFMA.
// z half (cols 128..255) stored direct from C frags; x half -> LDS -> conv epilogue.
__global__ __launch_bounds__(256) void k_stage1(
    const float* __restrict__ xT, const float* __restrict__ g1, const float* __restrict__ b1,
    const float* __restrict__ in_w, const float* __restrict__ in_b,
    const float* __restrict__ conv_w, const float* __restrict__ conv_b,
    float* __restrict__ xc, float* __restrict__ Zb){
  __shared__ __align__(16) __hip_bfloat16 xs[64][72];   // 9.2 KB
  __shared__ __align__(16) __hip_bfloat16 wt[256][72];  // 36.9 KB (cols 0..63 used)
  __shared__ __align__(16) float XZ[64][132];           // 33.8 KB (x_in half)
  int n = blockIdx.x;
  int b = n / WPB, wi = n % WPB;
  int wy = wi / NWX, wx = wi % NWX;
  int tid = threadIdx.x;
  // stage in_w transposed as bf16: in_w[c*256+o] -> wt[o][c]
  for (int idx = tid; idx < 16384; idx += 256) {
    int o = idx & 255, c = idx >> 8;
    wt[o][c] = (__hip_bfloat16)in_w[c*256 + o];
  }
  // LN1 (4 lanes per token, 16 ch each) -> xs bf16
  {
    int l = tid >> 2, q = tid & 3;
    int iy = l >> 3, ix = l & 7;
    int h = wy*8 + iy, w = wx*8 + ix;
    int hs = h + SHIFT; if (hs >= Hh) hs -= Hh;
    int ws2 = w + SHIFT; if (ws2 >= Ww) ws2 -= Ww;
    const float* src = xT + ((size_t)b*HWp + (size_t)hs*Ww + ws2) * 64 + q*16;
    float v[16];
    float s1 = 0.f, s2 = 0.f;
    #pragma unroll
    for (int k = 0; k < 4; k++) {
      float4 f = *reinterpret_cast<const float4*>(src + k*4);
      v[k*4+0]=f.x; v[k*4+1]=f.y; v[k*4+2]=f.z; v[k*4+3]=f.w;
    }
    #pragma unroll
    for (int i = 0; i < 16; i++) { s1 += v[i]; s2 += v[i]*v[i]; }
    s1 += __shfl_xor(s1, 1); s2 += __shfl_xor(s2, 1);
    s1 += __shfl_xor(s1, 2); s2 += __shfl_xor(s2, 2);
    float mu = s1 * (1.f/64.f);
    float var = s2 * (1.f/64.f) - mu*mu;
    float rstd = rsqrtf(var + 1e-5f);
    __hip_bfloat16 tmp[16];
    #pragma unroll
    for (int i = 0; i < 16; i++) {
      int c = q*16 + i;
      tmp[i] = (__hip_bfloat16)((v[i]-mu)*rstd*g1[c] + b1[c]);
    }
    *reinterpret_cast<short8v*>(&xs[l][q*16])     = *reinterpret_cast<short8v*>(&tmp[0]);
    *reinterpret_cast<short8v*>(&xs[l][q*16 + 8]) = *reinterpret_cast<short8v*>(&tmp[8]);
  }
  __syncthreads();
  // MFMA: wave w owns N-tiles w*4..w*4+3 (cols w*64..w*64+63)
  {
    int w = tid >> 6, lane = tid & 63;
    int col = lane & 15, g = lane >> 4;
    short8v af[4][2];
    #pragma unroll
    for (int m = 0; m < 4; m++)
      #pragma unroll
      for (int kh = 0; kh < 2; kh++)
        af[m][kh] = *reinterpret_cast<const short8v*>(&xs[m*16 + col][kh*32 + g*8]);
    f32x4 acc[4][4];
    #pragma unroll
    for (int m = 0; m < 4; m++)
      #pragma unroll
      for (int nt = 0; nt < 4; nt++)
        acc[m][nt] = (f32x4){0.f,0.f,0.f,0.f};
    #pragma unroll
    for (int nt = 0; nt < 4; nt++) {
      int o = (w*4 + nt)*16 + col;
      #pragma unroll
      for (int kh = 0; kh < 2; kh++) {
        short8v bf = *reinterpret_cast<const short8v*>(&wt[o][kh*32 + g*8]);
        #pragma unroll
        for (int m = 0; m < 4; m++)
          acc[m][nt] = __builtin_amdgcn_mfma_f32_16x16x32_bf16(af[m][kh], bf, acc[m][nt], 0, 0, 0);
      }
    }
    // write C
    #pragma unroll
    for (int nt = 0; nt < 4; nt++) {
      int colg = (w*4 + nt)*16 + col;
      float bias = in_b[colg];
      #pragma unroll
      for (int m = 0; m < 4; m++) {
        #pragma unroll
        for (int j = 0; j < 4; j++) {
          int row = m*16 + g*4 + j;
          float val = acc[m][nt][j] + bias;
          if (colg < 128) XZ[row][colg] = val;
          else Zb[((size_t)n*64 + row)*128 + (colg - 128)] = val;
        }
      }
    }
  }
  __syncthreads();
  // conv1d(K=4, causal) + silu epilogue: thread d walks 64 tokens
  if (tid < 128) {
    int d = tid;
    float cw0 = conv_w[d], cw1 = conv_w[128+d], cw2 = conv_w[256+d], cw3 = conv_w[384+d];
    float cb = conv_b[d];
    float p1 = 0.f, p2 = 0.f, p3 = 0.f;
    float* Xn = xc + (size_t)n*8192;
    #pragma unroll 4
    for (int t = 0; t < 64; t++) {
      int hh = wy*8 + (t>>3), ww2 = wx*8 + (t&7);
      float m = (hh < Hh-SHIFT && ww2 < Ww-SHIFT) ? 1.f : 0.f;
      float xv = XZ[t][d] * m;
      float pre = cw3*xv + cw2*p1 + cw1*p2 + cw0*p3 + cb;
      Xn[t*128 + d] = pre / (1.f + __expf(-pre));
      p3 = p2; p2 = p1; p1 = xv;
    }
  }
}

// ------------------- K3: dbc = xc @ xproj_w  (per-window 64x128 @ 128x36) -------------------
__global__ __launch_bounds__(256) void k_dbc(
    const float* __restrict__ xc, const float* __restrict__ xproj_w,
    float* __restrict__ dbc){
  __shared__ __align__(16) float xs[64][132];
  __shared__ float ws[128][37];
  int n = blockIdx.x;
  const float4* src = reinterpret_cast<const float4*>(xc + (size_t)n*8192);
  #pragma unroll
  for (int k = 0; k < 8; k++) {
    int gi = threadIdx.x + k*256;
    int t = gi >> 5, d4 = gi & 31;
    *reinterpret_cast<float4*>(&xs[t][d4*4]) = src[gi];
  }
  for (int idx = threadIdx.x; idx < 4608; idx += 256) {
    int c = idx / 36, j = idx - c*36;
    ws[c][j] = xproj_w[idx];
  }
  __syncthreads();
  int t = threadIdx.x >> 2, jq = threadIdx.x & 3;
  float acc[9];
  #pragma unroll
  for (int u = 0; u < 9; u++) acc[u] = 0.f;
  for (int c = 0; c < 128; c++) {
    float xv = xs[t][c];
    #pragma unroll
    for (int u = 0; u < 9; u++) acc[u] += xv * ws[c][jq*9+u];
  }
  float* dst = dbc + ((size_t)n*64 + t)*36 + jq*9;
  #pragma unroll
  for (int u = 0; u < 9; u++) dst[u] = acc[u];
}

// ------------------- K4: dt + selective scan + gate (1 thread per channel, 16 states in regs) -----
__global__ __launch_bounds__(128) void k_scan3(
    float* __restrict__ xc,           // in: xc ; out: g = (y + D*xc)*silu(z)
    const float* __restrict__ Zb, const float* __restrict__ dbc,
    const float* __restrict__ dt_w, const float* __restrict__ dt_b,
    const float* __restrict__ A_log, const float* __restrict__ Dp){
  __shared__ __align__(16) float db[64][40];
  int n = blockIdx.x;
  int d = threadIdx.x;  // 0..127
  const float4* dsrc = reinterpret_cast<const float4*>(dbc + (size_t)n*2304);
  for (int idx = threadIdx.x; idx < 576; idx += 128) {
    int t = idx / 9, j4 = idx - t*9;
    *reinterpret_cast<float4*>(&db[t][j4*4]) = dsrc[idx];
  }
  float dtb  = dt_b[d];
  float dtw0 = dt_w[d], dtw1 = dt_w[128+d], dtw2 = dt_w[256+d], dtw3 = dt_w[384+d];
  float Dd = Dp[d];
  float a[16];
  bool pow_ok = true;
  #pragma unroll
  for (int s = 0; s < 16; s++) {
    a[s] = -__expf(A_log[d*16+s]);
    pow_ok = pow_ok && (__builtin_fabsf(a[s] + (float)(s+1)) < 1e-3f);
  }
  float h[16];
  #pragma unroll
  for (int s = 0; s < 16; s++) h[s] = 0.f;
  const float* Xn = xc + (size_t)n*8192;
  const float* Zn = Zb + (size_t)n*8192;
  float* Gn = xc + (size_t)n*8192;
  __syncthreads();
  if (pow_ok) {
    #pragma unroll 4
    for (int i = 0; i < 64; i++) {
      float4 dv = *reinterpret_cast<const float4*>(&db[i][0]);
      float pre = dtb + dv.x*dtw0 + dv.y*dtw1 + dv.z*dtw2 + dv.w*dtw3;
      float dtv = (pre > 15.f) ? pre : __logf(1.f + __expf(pre));
      float xcv = Xn[i*128 + d];
      float zv  = Zn[i*128 + d];
      float du  = dtv * xcv;
      float P[16];
      P[0] = __expf(-dtv);
      #pragma unroll
      for (int s = 1; s < 16; s++) {
        int aa = (s-1) >> 1, bb = (s-1) - aa;
        P[s] = P[aa] * P[bb];
      }
      float4 B0 = *reinterpret_cast<const float4*>(&db[i][4]);
      float4 B1 = *reinterpret_cast<const float4*>(&db[i][8]);
      float4 B2 = *reinterpret_cast<const float4*>(&db[i][12]);
      float4 B3 = *reinterpret_cast<const float4*>(&db[i][16]);
      float4 C0 = *reinterpret_cast<const float4*>(&db[i][20]);
      float4 C1 = *reinterpret_cast<const float4*>(&db[i][24]);
      float4 C2 = *reinterpret_cast<const float4*>(&db[i][28]);
      float4 C3 = *reinterpret_cast<const float4*>(&db[i][32]);
      float y = 0.f;
      #pragma unroll
      for (int s = 0; s < 16; s++) {
        float Bs = (s < 4) ? ((const float*)&B0)[s] : (s < 8) ? ((const float*)&B1)[s-4]
                 : (s < 12) ? ((const float*)&B2)[s-8] : ((const float*)&B3)[s-12];
        float Cs = (s < 4) ? ((const float*)&C0)[s] : (s < 8) ? ((const float*)&C1)[s-4]
                 : (s < 12) ? ((const float*)&C2)[s-8] : ((const float*)&C3)[s-12];
        h[s] = P[s]*h[s] + du*Bs;
        y += h[s]*Cs;
      }
      float yv = y + Dd*xcv;
      Gn[i*128 + d] = yv * (zv / (1.f + __expf(-zv)));
    }
  } else {
    #pragma unroll 2
    for (int i = 0; i < 64; i++) {
      float4 dv = *reinterpret_cast<const float4*>(&db[i][0]);
      float pre = dtb + dv.x*dtw0 + dv.y*dtw1 + dv.z*dtw2 + dv.w*dtw3;
      float dtv = (pre > 15.f) ? pre : __logf(1.f + __expf(pre));
      float xcv = Xn[i*128 + d];
      float zv  = Zn[i*128 + d];
      float du  = dtv * xcv;
      float y = 0.f;
      #pragma unroll
      for (int s = 0; s < 16; s++) {
        float e = __expf(dtv * a[s]);
        h[s] = e*h[s] + du*db[i][4+s];
        y += h[s]*db[i][20+s];
      }
      float yv = y + Dd*xcv;
      Gn[i*128 + d] = yv * (zv / (1.f + __expf(-zv)));
    }
  }
}

// ------------------- K5: out_proj + window-reverse + skip1 + LN2 -------------------
__global__ __launch_bounds__(256) void k_out(
    const float* __restrict__ xT, const float* __restrict__ g,
    const float* __restrict__ out_w, const float* __restrict__ out_b,
    const float* __restrict__ skip1, const float* __restrict__ g2, const float* __restrict__ b2,
    float* __restrict__ x1, float* __restrict__ x2){
  __shared__ __align__(16) float gs[64][132];
  __shared__ float outs[64][65];
  int n = blockIdx.x;
  int b = n / WPB, wi = n % WPB;
  int wy = wi / NWX, wx = wi % NWX;
  const float4* src = reinterpret_cast<const float4*>(g + (size_t)n*8192);
  #pragma unroll
  for (int k = 0; k < 8; k++) {
    int gi = threadIdx.x + k*256;
    int t = gi >> 5, d4 = gi & 31;
    *reinterpret_cast<float4*>(&gs[t][d4*4]) = src[gi];
  }
  __syncthreads();
  int o = threadIdx.x & 63, tg = threadIdx.x >> 6;
  float acc[16];
  #pragma unroll
  for (int i = 0; i < 16; i++) acc[i] = 0.f;
  for (int c = 0; c < 128; c++) {
    float wv = out_w[c*64 + o];
    #pragma unroll
    for (int i = 0; i < 16; i++) acc[i] += gs[tg*16 + i][c] * wv;
  }
  float obv = out_b[o];
  #pragma unroll
  for (int i = 0; i < 16; i++) outs[tg*16 + i][o] = acc[i] + obv;
  __syncthreads();
  int l = threadIdx.x >> 2, q = threadIdx.x & 3;
  int hh = wy*8 + (l>>3), ww2 = wx*8 + (l&7);
  size_t T = (size_t)b*HWp + (size_t)hh*Ww + ww2;
  float v[16];
  float s1 = 0.f, s2 = 0.f;
  #pragma unroll
  for (int i = 0; i < 16; i++) {
    int c = q*16 + i;
    float val = xT[T*64 + c] * skip1[c] + outs[l][c];
    v[i] = val; s1 += val; s2 += val*val;
  }
  s1 += __shfl_xor(s1, 1); s2 += __shfl_xor(s2, 1);
  s1 += __shfl_xor(s1, 2); s2 += __shfl_xor(s2, 2);
  float mu = s1*(1.f/64.f);
  float var = s2*(1.f/64.f) - mu*mu;
  float rstd = rsqrtf(var + 1e-5f);
  #pragma unroll
  for (int i = 0; i < 16; i++) {
    int c = q*16 + i;
    x1[T*64 + c] = v[i];
    x2[T*64 + c] = (v[i]-mu)*rstd*g2[c] + b2[c];
  }
}

// ------------------- K6: CAB conv1 3x3 64->16 + gelu (bf16 MFMA implicit GEMM) -------------------
__global__ __launch_bounds__(256) void k_conv1(
    const float* __restrict__ x2, const float* __restrict__ w1, const float* __restrict__ bc1,
    __hip_bfloat16* __restrict__ c1){
  __shared__ __align__(16) __hip_bfloat16 xt[100][72];   // 14.4 KB
  __shared__ __align__(16) __hip_bfloat16 wt[9][16][72]; // 20.7 KB [tap][co][ci] (pad 72)
  int b = blockIdx.x / WPB;
  int r = blockIdx.x % WPB;
  int by = r / NWX, bx = r % NWX;
  for (int idx = threadIdx.x; idx < 9216; idx += 256) {
    int co = idx / 576, rest = idx % 576;
    int ci = rest / 9, tap = rest % 9;
    wt[tap][co][ci] = (__hip_bfloat16)w1[idx];
  }
  for (int idx = threadIdx.x; idx < 1600; idx += 256) {
    int p = idx >> 4, c4 = idx & 15;
    int gy = by*8 + p/10 - 1;
    int gx = bx*8 + p%10 - 1;
    float4 v = make_float4(0.f,0.f,0.f,0.f);
    if (gy >= 0 && gy < Hh && gx >= 0 && gx < Ww)
      v = *reinterpret_cast<const float4*>(&x2[((size_t)b*HWp + (size_t)gy*Ww + gx)*64 + c4*4]);
    __hip_bfloat16 tmp[4] = {(__hip_bfloat16)v.x,(__hip_bfloat16)v.y,(__hip_bfloat16)v.z,(__hip_bfloat16)v.w};
    *reinterpret_cast<ushort4*>(&xt[p][c4*4]) = *reinterpret_cast<ushort4*>(tmp);
  }
  __syncthreads();
  int wv = threadIdx.x >> 6;
  int l  = threadIdx.x & 63;
  int col = l & 15, g = l >> 4;
  int apix = wv*16 + col;
  int apy = apix >> 3, apx = apix & 7;
  f32x4 acc = {0.f,0.f,0.f,0.f};
  #pragma unroll
  for (int tap = 0; tap < 9; tap++) {
    int ky = tap/3, kx = tap%3;
    const __hip_bfloat16* arow = &xt[(apy+ky)*10 + apx+kx][0];
    #pragma unroll
    for (int kh = 0; kh < 2; kh++) {
      short8v af = *reinterpret_cast<const short8v*>(&arow[kh*32 + g*8]);
      short8v bf = *reinterpret_cast<const short8v*>(&wt[tap][col][kh*32 + g*8]);
      acc = __builtin_amdgcn_mfma_f32_16x16x32_bf16(af, bf, acc, 0, 0, 0);
    }
  }
  float bias = bc1[col];
  #pragma unroll
  for (int j = 0; j < 4; j++) {
    int opix = wv*16 + g*4 + j;
    int oy = by*8 + (opix>>3), ox = bx*8 + (opix&7);
    float v = acc[j] + bias;
    float gv = 0.5f * v * (1.f + erff(v * 0.70710678118f));
    c1[((size_t)b*HWp + (size_t)oy*Ww + ox)*16 + col] = (__hip_bfloat16)gv;
  }
}

// ------------------- K7: CAB conv2 3x3 16->64 + partial mean (bf16 MFMA implicit GEMM) ------------
__global__ __launch_bounds__(256) void k_conv2(
    const __hip_bfloat16* __restrict__ c1, const float* __restrict__ w2, const float* __restrict__ bc2,
    float* __restrict__ c2, float* __restrict__ sums){
  __shared__ __align__(16) __hip_bfloat16 xt[100][16];   // 3.2 KB
  __shared__ __align__(16) __hip_bfloat16 wt[5][64][40]; // 25.6 KB [pair][co][k] (pad 40)
  __shared__ float red[4][64];
  int b = blockIdx.x / WPB;
  int r = blockIdx.x % WPB;
  int by = r / NWX, bx = r % NWX;
  for (int idx = threadIdx.x; idx < 10240; idx += 256) {
    int k = idx & 31, co = (idx >> 5) & 63, p = idx >> 11;
    int tap = p*2 + (k >> 4);
    int ci = k & 15;
    float wv = (tap < 9) ? w2[co*144 + ci*9 + tap] : 0.f;
    wt[p][co][k] = (__hip_bfloat16)wv;
  }
  for (int idx = threadIdx.x; idx < 400; idx += 256) {
    int p = idx >> 2, c4 = idx & 3;
    int gy = by*8 + p/10 - 1;
    int gx = bx*8 + p%10 - 1;
    ushort4 v = {0,0,0,0};
    if (gy >= 0 && gy < Hh && gx >= 0 && gx < Ww)
      v = *reinterpret_cast<const ushort4*>(&c1[((size_t)b*HWp + (size_t)gy*Ww + gx)*16 + c4*4]);
    *reinterpret_cast<ushort4*>(&xt[p][c4*4]) = v;
  }
  __syncthreads();
  int wv4 = threadIdx.x >> 6;
  int l   = threadIdx.x & 63;
  int col = l & 15, g = l >> 4;
  int apix = wv4*16 + col;
  int apy = apix >> 3, apx = apix & 7;
  f32x4 acc[4] = {{0.f,0.f,0.f,0.f},{0.f,0.f,0.f,0.f},{0.f,0.f,0.f,0.f},{0.f,0.f,0.f,0.f}};
  #pragma unroll
  for (int p = 0; p < 5; p++) {
    int tap = p*2 + (g >> 1); if (tap > 8) tap = 8;
    int ky = tap/3, kx = tap%3;
    short8v af = *reinterpret_cast<const short8v*>(&xt[(apy+ky)*10 + apx+kx][(g&1)*8]);
    #pragma unroll
    for (int ct = 0; ct < 4; ct++) {
      short8v bf = *reinterpret_cast<const short8v*>(&wt[p][ct*16 + col][g*8]);
      acc[ct] = __builtin_amdgcn_mfma_f32_16x16x32_bf16(af, bf, acc[ct], 0, 0, 0);
    }
  }
  #pragma unroll
  for (int ct = 0; ct < 4; ct++) {
    int co = ct*16 + col;
    float bias = bc2[co];
    float part = 0.f;
    #pragma unroll
    for (int j = 0; j < 4; j++) {
      int opix = wv4*16 + g*4 + j;
      int oy = by*8 + (opix>>3), ox = bx*8 + (opix&7);
      float v = acc[ct][j] + bias;
      c2[((size_t)b*HWp + (size_t)oy*Ww + ox)*64 + co] = v;
      part += v;
    }
    part += __shfl_xor(part, 16);
    part += __shfl_xor(part, 32);
    if (g == 0) red[wv4][co] = part;
  }
  __syncthreads();
  if (threadIdx.x < 64) {
    float s = red[0][threadIdx.x] + red[1][threadIdx.x] + red[2][threadIdx.x] + red[3][threadIdx.x];
    atomicAdd(&sums[b*64 + threadIdx.x], s);
  }
}

// ------------------- K8: channel attention -------------------
__global__ void k_att(const float* __restrict__ sums,
                      const float* __restrict__ wd, const float* __restrict__ bd,
                      const float* __restrict__ wu, const float* __restrict__ bu,
                      float* __restrict__ att){
  int tid = threadIdx.x;            // 128 threads
  int b = tid >> 6, co = tid & 63;
  float inv = 1.f / (float)HWp;
  float hid[4];
  #pragma unroll
  for (int j = 0; j < 4; j++) {
    float acc = bd[j];
    for (int c = 0; c < 64; c++) acc += wd[j*64+c] * (sums[b*64+c] * inv);
    hid[j] = fmaxf(acc, 0.f);
  }
  float acc = bu[co];
  #pragma unroll
  for (int j = 0; j < 4; j++) acc += wu[co*4+j] * hid[j];
  att[tid] = 1.f / (1.f + __expf(-acc));
}

// ------------------- K9: final combine + NHWC -> NCHW -------------------
__global__ __launch_bounds__(256) void k_final(
    const float* __restrict__ x1, const float* __restrict__ c2,
    const float* __restrict__ skip2, const float* __restrict__ att,
    float* __restrict__ out){
  __shared__ float t[64][65];
  int b = blockIdx.x / WPB;
  int hw0 = (blockIdx.x % WPB) * 64;
  int lane = threadIdx.x & 63, grp = threadIdx.x >> 6;
  float sk = skip2[lane], at = att[b*64 + lane];
  #pragma unroll
  for (int r = 0; r < 64; r += 4) {
    int hwl = r + grp;
    size_t T = (size_t)b*HWp + hw0 + hwl;
    t[hwl][lane] = x1[T*64+lane]*sk + c2[T*64+lane]*at;
  }
  __syncthreads();
  float* ob = out + (size_t)b * Cch * HWp;
  #pragma unroll
  for (int r = 0; r < 64; r += 4) {
    int c = r + grp;
    ob[(size_t)c*HWp + hw0 + lane] = t[lane][c];
  }
}

extern "C" void kernel_launch(void* const* d_in, const int* in_sizes, int n_in,
                              void* d_out, int out_size, void* d_ws, size_t ws_size,
                              hipStream_t stream) {
  (void)in_sizes; (void)n_in; (void)out_size; (void)ws_size;
  const float* x      = (const float*)d_in[0];
  const float* ln1_g  = (const float*)d_in[1];
  const float* ln1_b  = (const float*)d_in[2];
  const float* in_w   = (const float*)d_in[3];
  const float* in_b   = (const float*)d_in[4];
  const float* conv_w = (const float*)d_in[5];
  const float* conv_b = (const float*)d_in[6];
  const float* xproj_w= (const float*)d_in[7];
  const float* dt_w   = (const float*)d_in[8];
  const float* dt_b   = (const float*)d_in[9];
  const float* A_log  = (const float*)d_in[10];
  const float* Dp     = (const float*)d_in[11];
  const float* out_w  = (const float*)d_in[12];
  const float* out_b  = (const float*)d_in[13];
  const float* skip1  = (const float*)d_in[14];
  const float* ln2_g  = (const float*)d_in[15];
  const float* ln2_b  = (const float*)d_in[16];
  const float* skip2  = (const float*)d_in[17];
  const float* cab_w1 = (const float*)d_in[18];
  const float* cab_b1 = (const float*)d_in[19];
  const float* cab_w2 = (const float*)d_in[20];
  const float* cab_b2 = (const float*)d_in[21];
  const float* ca_wd  = (const float*)d_in[22];
  const float* ca_bd  = (const float*)d_in[23];
  const float* ca_wu  = (const float*)d_in[24];
  const float* ca_bu  = (const float*)d_in[25];

  float* ws   = (float*)d_ws;
  float* xT   = ws;                        // [0, 4718592)
  float* xc   = ws + 4718592;              // g in-place; c2 aliases later
  float* z    = ws + 14155776;             // x1/x2 alias later
  float* dbc  = ws + 23592960;             // c1 aliases later
  float* sums = ws + 26247168;             // 128
  float* att  = ws + 26247296;             // 128
  float* x1   = ws + 14155776;             // alias over z
  float* x2   = ws + 18874368;             // alias over z second half
  __hip_bfloat16* c1 = (__hip_bfloat16*)(ws + 23592960); // alias over dbc
  float* c2   = ws + 4718592;              // alias over xc/g

  hipMemsetAsync(sums, 0, 128*sizeof(float), stream);
  k_transpose<<<NW, 256, 0, stream>>>(x, xT);
  k_stage1<<<NW, 256, 0, stream>>>(xT, ln1_g, ln1_b, in_w, in_b, conv_w, conv_b, xc, z);
  k_dbc<<<NW, 256, 0, stream>>>(xc, xproj_w, dbc);
  k_scan3<<<NW, 128, 0, stream>>>(xc, z, dbc, dt_w, dt_b, A_log, Dp);
  k_out<<<NW, 256, 0, stream>>>(xT, xc, out_w, out_b, skip1, ln2_g, ln2_b, x1, x2);
  k_conv1<<<NW, 256, 0, stream>>>(x2, cab_w1, cab_b1, c1);
  k_conv2<<<NW, 256, 0, stream>>>(c1, cab_w2, cab_b2, c2, sums);
  k_att<<<1, 128, 0, stream>>>(sums, ca_wd, ca_bd, ca_wu, ca_bu, att);
  k_final<<<NW, 256, 0, stream>>>(x1, c2, skip2, att, (float*)d_out);
}

// Round 9
// 229.695 us; speedup vs baseline: 2.1897x; 1.0645x over previous
//
#include <hip/hip_runtime.h>
#include <hip/hip_bf16.h>
#include <math.h>

// Problem constants
#define Hh 192
#define Ww 192
#define HWp (Hh*Ww)          // 36864
#define Bb 2
#define Cch 64
#define DI 128
#define NWX 24               // windows per row
#define WPB 576              // windows per batch
#define NW  1152             // total windows
#define DS 16
#define SHIFT 4

typedef __attribute__((ext_vector_type(8))) short short8v;  // 8 bf16 (4 VGPRs)
typedef __attribute__((ext_vector_type(4))) float f32x4;    // MFMA accumulator

// ------------------- K1: NCHW -> NHWC transpose -------------------
__global__ __launch_bounds__(256) void k_transpose(const float* __restrict__ x, float* __restrict__ xT){
  __shared__ float t[64][65];
  int b   = blockIdx.x / WPB;
  int hw0 = (blockIdx.x % WPB) * 64;
  int lane = threadIdx.x & 63, grp = threadIdx.x >> 6;
  const float* xb = x + (size_t)b * Cch * HWp;
  #pragma unroll
  for (int r = 0; r < 64; r += 4) {
    int c = r + grp;
    t[c][lane] = xb[(size_t)c * HWp + hw0 + lane];
  }
  __syncthreads();
  float* xo = xT + ((size_t)b * HWp + hw0) * 64;
  #pragma unroll
  for (int r = 0; r < 64; r += 4) {
    int hwl = r + grp;
    xo[(size_t)hwl * 64 + lane] = t[lane][hwl];
  }
}

// ------------------- K2: shift + LN1 + in_proj(MFMA bf16) + mask + conv1d + silu -------------------
__global__ __launch_bounds__(256) void k_stage1(
    const float* __restrict__ xT, const float* __restrict__ g1, const float* __restrict__ b1,
    const float* __restrict__ in_w, const float* __restrict__ in_b,
    const float* __restrict__ conv_w, const float* __restrict__ conv_b,
    float* __restrict__ xc, float* __restrict__ Zb){
  __shared__ __align__(16) __hip_bfloat16 xs[64][72];   // 9.2 KB
  __shared__ __align__(16) __hip_bfloat16 wt[256][72];  // 36.9 KB (cols 0..63 used)
  __shared__ __align__(16) float XZ[64][132];           // 33.8 KB (x_in half)
  int n = blockIdx.x;
  int b = n / WPB, wi = n % WPB;
  int wy = wi / NWX, wx = wi % NWX;
  int tid = threadIdx.x;
  for (int idx = tid; idx < 16384; idx += 256) {
    int o = idx & 255, c = idx >> 8;
    wt[o][c] = (__hip_bfloat16)in_w[c*256 + o];
  }
  {
    int l = tid >> 2, q = tid & 3;
    int iy = l >> 3, ix = l & 7;
    int h = wy*8 + iy, w = wx*8 + ix;
    int hs = h + SHIFT; if (hs >= Hh) hs -= Hh;
    int ws2 = w + SHIFT; if (ws2 >= Ww) ws2 -= Ww;
    const float* src = xT + ((size_t)b*HWp + (size_t)hs*Ww + ws2) * 64 + q*16;
    float v[16];
    float s1 = 0.f, s2 = 0.f;
    #pragma unroll
    for (int k = 0; k < 4; k++) {
      float4 f = *reinterpret_cast<const float4*>(src + k*4);
      v[k*4+0]=f.x; v[k*4+1]=f.y; v[k*4+2]=f.z; v[k*4+3]=f.w;
    }
    #pragma unroll
    for (int i = 0; i < 16; i++) { s1 += v[i]; s2 += v[i]*v[i]; }
    s1 += __shfl_xor(s1, 1); s2 += __shfl_xor(s2, 1);
    s1 += __shfl_xor(s1, 2); s2 += __shfl_xor(s2, 2);
    float mu = s1 * (1.f/64.f);
    float var = s2 * (1.f/64.f) - mu*mu;
    float rstd = rsqrtf(var + 1e-5f);
    __hip_bfloat16 tmp[16];
    #pragma unroll
    for (int i = 0; i < 16; i++) {
      int c = q*16 + i;
      tmp[i] = (__hip_bfloat16)((v[i]-mu)*rstd*g1[c] + b1[c]);
    }
    *reinterpret_cast<short8v*>(&xs[l][q*16])     = *reinterpret_cast<short8v*>(&tmp[0]);
    *reinterpret_cast<short8v*>(&xs[l][q*16 + 8]) = *reinterpret_cast<short8v*>(&tmp[8]);
  }
  __syncthreads();
  {
    int w = tid >> 6, lane = tid & 63;
    int col = lane & 15, g = lane >> 4;
    short8v af[4][2];
    #pragma unroll
    for (int m = 0; m < 4; m++)
      #pragma unroll
      for (int kh = 0; kh < 2; kh++)
        af[m][kh] = *reinterpret_cast<const short8v*>(&xs[m*16 + col][kh*32 + g*8]);
    f32x4 acc[4][4];
    #pragma unroll
    for (int m = 0; m < 4; m++)
      #pragma unroll
      for (int nt = 0; nt < 4; nt++)
        acc[m][nt] = (f32x4){0.f,0.f,0.f,0.f};
    #pragma unroll
    for (int nt = 0; nt < 4; nt++) {
      int o = (w*4 + nt)*16 + col;
      #pragma unroll
      for (int kh = 0; kh < 2; kh++) {
        short8v bf = *reinterpret_cast<const short8v*>(&wt[o][kh*32 + g*8]);
        #pragma unroll
        for (int m = 0; m < 4; m++)
          acc[m][nt] = __builtin_amdgcn_mfma_f32_16x16x32_bf16(af[m][kh], bf, acc[m][nt], 0, 0, 0);
      }
    }
    #pragma unroll
    for (int nt = 0; nt < 4; nt++) {
      int colg = (w*4 + nt)*16 + col;
      float bias = in_b[colg];
      #pragma unroll
      for (int m = 0; m < 4; m++) {
        #pragma unroll
        for (int j = 0; j < 4; j++) {
          int row = m*16 + g*4 + j;
          float val = acc[m][nt][j] + bias;
          if (colg < 128) XZ[row][colg] = val;
          else Zb[((size_t)n*64 + row)*128 + (colg - 128)] = val;
        }
      }
    }
  }
  __syncthreads();
  if (tid < 128) {
    int d = tid;
    float cw0 = conv_w[d], cw1 = conv_w[128+d], cw2 = conv_w[256+d], cw3 = conv_w[384+d];
    float cb = conv_b[d];
    float p1 = 0.f, p2 = 0.f, p3 = 0.f;
    float* Xn = xc + (size_t)n*8192;
    #pragma unroll 4
    for (int t = 0; t < 64; t++) {
      int hh = wy*8 + (t>>3), ww2 = wx*8 + (t&7);
      float m = (hh < Hh-SHIFT && ww2 < Ww-SHIFT) ? 1.f : 0.f;
      float xv = XZ[t][d] * m;
      float pre = cw3*xv + cw2*p1 + cw1*p2 + cw0*p3 + cb;
      Xn[t*128 + d] = pre / (1.f + __expf(-pre));
      p3 = p2; p2 = p1; p1 = xv;
    }
  }
}

// ------------------- K3: dbc = xc @ xproj_w  (per-window 64x128 @ 128x36) -------------------
__global__ __launch_bounds__(256) void k_dbc(
    const float* __restrict__ xc, const float* __restrict__ xproj_w,
    float* __restrict__ dbc){
  __shared__ __align__(16) float xs[64][132];
  __shared__ float ws[128][37];
  int n = blockIdx.x;
  const float4* src = reinterpret_cast<const float4*>(xc + (size_t)n*8192);
  #pragma unroll
  for (int k = 0; k < 8; k++) {
    int gi = threadIdx.x + k*256;
    int t = gi >> 5, d4 = gi & 31;
    *reinterpret_cast<float4*>(&xs[t][d4*4]) = src[gi];
  }
  for (int idx = threadIdx.x; idx < 4608; idx += 256) {
    int c = idx / 36, j = idx - c*36;
    ws[c][j] = xproj_w[idx];
  }
  __syncthreads();
  int t = threadIdx.x >> 2, jq = threadIdx.x & 3;
  float acc[9];
  #pragma unroll
  for (int u = 0; u < 9; u++) acc[u] = 0.f;
  for (int c = 0; c < 128; c++) {
    float xv = xs[t][c];
    #pragma unroll
    for (int u = 0; u < 9; u++) acc[u] += xv * ws[c][jq*9+u];
  }
  float* dst = dbc + ((size_t)n*64 + t)*36 + jq*9;
  #pragma unroll
  for (int u = 0; u < 9; u++) dst[u] = acc[u];
}

// ------------------- K4: dt + selective scan + gate (1 thread per channel, 16 states in regs) -----
__global__ __launch_bounds__(128) void k_scan3(
    float* __restrict__ xc,           // in: xc ; out: g = (y + D*xc)*silu(z)
    const float* __restrict__ Zb, const float* __restrict__ dbc,
    const float* __restrict__ dt_w, const float* __restrict__ dt_b,
    const float* __restrict__ A_log, const float* __restrict__ Dp){
  __shared__ __align__(16) float db[64][40];
  int n = blockIdx.x;
  int d = threadIdx.x;  // 0..127
  const float4* dsrc = reinterpret_cast<const float4*>(dbc + (size_t)n*2304);
  for (int idx = threadIdx.x; idx < 576; idx += 128) {
    int t = idx / 9, j4 = idx - t*9;
    *reinterpret_cast<float4*>(&db[t][j4*4]) = dsrc[idx];
  }
  float dtb  = dt_b[d];
  float dtw0 = dt_w[d], dtw1 = dt_w[128+d], dtw2 = dt_w[256+d], dtw3 = dt_w[384+d];
  float Dd = Dp[d];
  float a[16];
  bool pow_ok = true;
  #pragma unroll
  for (int s = 0; s < 16; s++) {
    a[s] = -__expf(A_log[d*16+s]);
    pow_ok = pow_ok && (__builtin_fabsf(a[s] + (float)(s+1)) < 1e-3f);
  }
  float h[16];
  #pragma unroll
  for (int s = 0; s < 16; s++) h[s] = 0.f;
  const float* Xn = xc + (size_t)n*8192;
  const float* Zn = Zb + (size_t)n*8192;
  float* Gn = xc + (size_t)n*8192;
  __syncthreads();
  if (pow_ok) {
    #pragma unroll 4
    for (int i = 0; i < 64; i++) {
      float4 dv = *reinterpret_cast<const float4*>(&db[i][0]);
      float pre = dtb + dv.x*dtw0 + dv.y*dtw1 + dv.z*dtw2 + dv.w*dtw3;
      float dtv = (pre > 15.f) ? pre : __logf(1.f + __expf(pre));
      float xcv = Xn[i*128 + d];
      float zv  = Zn[i*128 + d];
      float du  = dtv * xcv;
      float P[16];
      P[0] = __expf(-dtv);
      #pragma unroll
      for (int s = 1; s < 16; s++) {
        int aa = (s-1) >> 1, bb = (s-1) - aa;
        P[s] = P[aa] * P[bb];
      }
      float4 B0 = *reinterpret_cast<const float4*>(&db[i][4]);
      float4 B1 = *reinterpret_cast<const float4*>(&db[i][8]);
      float4 B2 = *reinterpret_cast<const float4*>(&db[i][12]);
      float4 B3 = *reinterpret_cast<const float4*>(&db[i][16]);
      float4 C0 = *reinterpret_cast<const float4*>(&db[i][20]);
      float4 C1 = *reinterpret_cast<const float4*>(&db[i][24]);
      float4 C2 = *reinterpret_cast<const float4*>(&db[i][28]);
      float4 C3 = *reinterpret_cast<const float4*>(&db[i][32]);
      float y = 0.f;
      #pragma unroll
      for (int s = 0; s < 16; s++) {
        float Bs = (s < 4) ? ((const float*)&B0)[s] : (s < 8) ? ((const float*)&B1)[s-4]
                 : (s < 12) ? ((const float*)&B2)[s-8] : ((const float*)&B3)[s-12];
        float Cs = (s < 4) ? ((const float*)&C0)[s] : (s < 8) ? ((const float*)&C1)[s-4]
                 : (s < 12) ? ((const float*)&C2)[s-8] : ((const float*)&C3)[s-12];
        h[s] = P[s]*h[s] + du*Bs;
        y += h[s]*Cs;
      }
      float yv = y + Dd*xcv;
      Gn[i*128 + d] = yv * (zv / (1.f + __expf(-zv)));
    }
  } else {
    #pragma unroll 2
    for (int i = 0; i < 64; i++) {
      float4 dv = *reinterpret_cast<const float4*>(&db[i][0]);
      float pre = dtb + dv.x*dtw0 + dv.y*dtw1 + dv.z*dtw2 + dv.w*dtw3;
      float dtv = (pre > 15.f) ? pre : __logf(1.f + __expf(pre));
      float xcv = Xn[i*128 + d];
      float zv  = Zn[i*128 + d];
      float du  = dtv * xcv;
      float y = 0.f;
      #pragma unroll
      for (int s = 0; s < 16; s++) {
        float e = __expf(dtv * a[s]);
        h[s] = e*h[s] + du*db[i][4+s];
        y += h[s]*db[i][20+s];
      }
      float yv = y + Dd*xcv;
      Gn[i*128 + d] = yv * (zv / (1.f + __expf(-zv)));
    }
  }
}

// ------------------- K5: out_proj (bf16 MFMA) + window-reverse + skip1 + LN2 -------------------
// 4 waves: wave w owns tokens w*16..w*16+15, all 4 N-tiles, K=128 (4 K-steps) = 16 MFMA.
__global__ __launch_bounds__(256) void k_out(
    const float* __restrict__ xT, const float* __restrict__ g,
    const float* __restrict__ out_w, const float* __restrict__ out_b,
    const float* __restrict__ skip1, const float* __restrict__ g2, const float* __restrict__ b2,
    float* __restrict__ x1, float* __restrict__ x2){
  __shared__ __align__(16) __hip_bfloat16 gs[64][136];  // 17.4 KB
  __shared__ __align__(16) __hip_bfloat16 wt[64][136];  // 17.4 KB (out_w^T)
  __shared__ float outs[64][65];                        // 16.6 KB
  int n = blockIdx.x;
  int b = n / WPB, wi = n % WPB;
  int wy = wi / NWX, wx = wi % NWX;
  int tid = threadIdx.x;
  // stage g (fp32 -> bf16)
  const float4* src = reinterpret_cast<const float4*>(g + (size_t)n*8192);
  #pragma unroll
  for (int k = 0; k < 8; k++) {
    int gi = tid + k*256;
    int t = gi >> 5, d4 = gi & 31;
    float4 v = src[gi];
    __hip_bfloat16 tmp[4] = {(__hip_bfloat16)v.x,(__hip_bfloat16)v.y,(__hip_bfloat16)v.z,(__hip_bfloat16)v.w};
    *reinterpret_cast<ushort4*>(&gs[t][d4*4]) = *reinterpret_cast<ushort4*>(tmp);
  }
  // stage out_w^T: out_w[c*64+o] -> wt[o][c]
  for (int idx = tid; idx < 8192; idx += 256) {
    int o = idx & 63, c = idx >> 6;
    wt[o][c] = (__hip_bfloat16)out_w[idx];
  }
  __syncthreads();
  {
    int w = tid >> 6, lane = tid & 63;
    int col = lane & 15, gq = lane >> 4;
    f32x4 acc[4] = {{0.f,0.f,0.f,0.f},{0.f,0.f,0.f,0.f},{0.f,0.f,0.f,0.f},{0.f,0.f,0.f,0.f}};
    #pragma unroll
    for (int kh = 0; kh < 4; kh++) {
      short8v af = *reinterpret_cast<const short8v*>(&gs[w*16 + col][kh*32 + gq*8]);
      #pragma unroll
      for (int nt = 0; nt < 4; nt++) {
        short8v bf = *reinterpret_cast<const short8v*>(&wt[nt*16 + col][kh*32 + gq*8]);
        acc[nt] = __builtin_amdgcn_mfma_f32_16x16x32_bf16(af, bf, acc[nt], 0, 0, 0);
      }
    }
    #pragma unroll
    for (int nt = 0; nt < 4; nt++) {
      int o = nt*16 + col;
      float bias = out_b[o];
      #pragma unroll
      for (int j = 0; j < 4; j++)
        outs[w*16 + gq*4 + j][o] = acc[nt][j] + bias;
    }
  }
  __syncthreads();
  // skip1 + LN2 epilogue (4 lanes per token)
  int l = tid >> 2, q = tid & 3;
  int hh = wy*8 + (l>>3), ww2 = wx*8 + (l&7);
  size_t T = (size_t)b*HWp + (size_t)hh*Ww + ww2;
  float v[16];
  float s1 = 0.f, s2 = 0.f;
  #pragma unroll
  for (int i = 0; i < 16; i++) {
    int c = q*16 + i;
    float val = xT[T*64 + c] * skip1[c] + outs[l][c];
    v[i] = val; s1 += val; s2 += val*val;
  }
  s1 += __shfl_xor(s1, 1); s2 += __shfl_xor(s2, 1);
  s1 += __shfl_xor(s1, 2); s2 += __shfl_xor(s2, 2);
  float mu = s1*(1.f/64.f);
  float var = s2*(1.f/64.f) - mu*mu;
  float rstd = rsqrtf(var + 1e-5f);
  #pragma unroll
  for (int i = 0; i < 16; i++) {
    int c = q*16 + i;
    x1[T*64 + c] = v[i];
    x2[T*64 + c] = (v[i]-mu)*rstd*g2[c] + b2[c];
  }
}

// ------------------- K6: CAB conv1 3x3 64->16 + gelu (bf16 MFMA implicit GEMM) -------------------
__global__ __launch_bounds__(256) void k_conv1(
    const float* __restrict__ x2, const float* __restrict__ w1, const float* __restrict__ bc1,
    __hip_bfloat16* __restrict__ c1){
  __shared__ __align__(16) __hip_bfloat16 xt[100][72];   // 14.4 KB
  __shared__ __align__(16) __hip_bfloat16 wt[9][16][72]; // 20.7 KB [tap][co][ci] (pad 72)
  int b = blockIdx.x / WPB;
  int r = blockIdx.x % WPB;
  int by = r / NWX, bx = r % NWX;
  for (int idx = threadIdx.x; idx < 9216; idx += 256) {
    int co = idx / 576, rest = idx % 576;
    int ci = rest / 9, tap = rest % 9;
    wt[tap][co][ci] = (__hip_bfloat16)w1[idx];
  }
  for (int idx = threadIdx.x; idx < 1600; idx += 256) {
    int p = idx >> 4, c4 = idx & 15;
    int gy = by*8 + p/10 - 1;
    int gx = bx*8 + p%10 - 1;
    float4 v = make_float4(0.f,0.f,0.f,0.f);
    if (gy >= 0 && gy < Hh && gx >= 0 && gx < Ww)
      v = *reinterpret_cast<const float4*>(&x2[((size_t)b*HWp + (size_t)gy*Ww + gx)*64 + c4*4]);
    __hip_bfloat16 tmp[4] = {(__hip_bfloat16)v.x,(__hip_bfloat16)v.y,(__hip_bfloat16)v.z,(__hip_bfloat16)v.w};
    *reinterpret_cast<ushort4*>(&xt[p][c4*4]) = *reinterpret_cast<ushort4*>(tmp);
  }
  __syncthreads();
  int wv = threadIdx.x >> 6;
  int l  = threadIdx.x & 63;
  int col = l & 15, g = l >> 4;
  int apix = wv*16 + col;
  int apy = apix >> 3, apx = apix & 7;
  f32x4 acc = {0.f,0.f,0.f,0.f};
  #pragma unroll
  for (int tap = 0; tap < 9; tap++) {
    int ky = tap/3, kx = tap%3;
    const __hip_bfloat16* arow = &xt[(apy+ky)*10 + apx+kx][0];
    #pragma unroll
    for (int kh = 0; kh < 2; kh++) {
      short8v af = *reinterpret_cast<const short8v*>(&arow[kh*32 + g*8]);
      short8v bf = *reinterpret_cast<const short8v*>(&wt[tap][col][kh*32 + g*8]);
      acc = __builtin_amdgcn_mfma_f32_16x16x32_bf16(af, bf, acc, 0, 0, 0);
    }
  }
  float bias = bc1[col];
  #pragma unroll
  for (int j = 0; j < 4; j++) {
    int opix = wv*16 + g*4 + j;
    int oy = by*8 + (opix>>3), ox = bx*8 + (opix&7);
    float v = acc[j] + bias;
    float gv = 0.5f * v * (1.f + erff(v * 0.70710678118f));
    c1[((size_t)b*HWp + (size_t)oy*Ww + ox)*16 + col] = (__hip_bfloat16)gv;
  }
}

// ------------------- K7: CAB conv2 3x3 16->64 + partial mean (bf16 MFMA implicit GEMM) ------------
__global__ __launch_bounds__(256) void k_conv2(
    const __hip_bfloat16* __restrict__ c1, const float* __restrict__ w2, const float* __restrict__ bc2,
    float* __restrict__ c2, float* __restrict__ sums){
  __shared__ __align__(16) __hip_bfloat16 xt[100][16];   // 3.2 KB
  __shared__ __align__(16) __hip_bfloat16 wt[5][64][40]; // 25.6 KB [pair][co][k] (pad 40)
  __shared__ float red[4][64];
  int b = blockIdx.x / WPB;
  int r = blockIdx.x % WPB;
  int by = r / NWX, bx = r % NWX;
  for (int idx = threadIdx.x; idx < 10240; idx += 256) {
    int k = idx & 31, co = (idx >> 5) & 63, p = idx >> 11;
    int tap = p*2 + (k >> 4);
    int ci = k & 15;
    float wv = (tap < 9) ? w2[co*144 + ci*9 + tap] : 0.f;
    wt[p][co][k] = (__hip_bfloat16)wv;
  }
  for (int idx = threadIdx.x; idx < 400; idx += 256) {
    int p = idx >> 2, c4 = idx & 3;
    int gy = by*8 + p/10 - 1;
    int gx = bx*8 + p%10 - 1;
    ushort4 v = {0,0,0,0};
    if (gy >= 0 && gy < Hh && gx >= 0 && gx < Ww)
      v = *reinterpret_cast<const ushort4*>(&c1[((size_t)b*HWp + (size_t)gy*Ww + gx)*16 + c4*4]);
    *reinterpret_cast<ushort4*>(&xt[p][c4*4]) = v;
  }
  __syncthreads();
  int wv4 = threadIdx.x >> 6;
  int l   = threadIdx.x & 63;
  int col = l & 15, g = l >> 4;
  int apix = wv4*16 + col;
  int apy = apix >> 3, apx = apix & 7;
  f32x4 acc[4] = {{0.f,0.f,0.f,0.f},{0.f,0.f,0.f,0.f},{0.f,0.f,0.f,0.f},{0.f,0.f,0.f,0.f}};
  #pragma unroll
  for (int p = 0; p < 5; p++) {
    int tap = p*2 + (g >> 1); if (tap > 8) tap = 8;
    int ky = tap/3, kx = tap%3;
    short8v af = *reinterpret_cast<const short8v*>(&xt[(apy+ky)*10 + apx+kx][(g&1)*8]);
    #pragma unroll
    for (int ct = 0; ct < 4; ct++) {
      short8v bf = *reinterpret_cast<const short8v*>(&wt[p][ct*16 + col][g*8]);
      acc[ct] = __builtin_amdgcn_mfma_f32_16x16x32_bf16(af, bf, acc[ct], 0, 0, 0);
    }
  }
  #pragma unroll
  for (int ct = 0; ct < 4; ct++) {
    int co = ct*16 + col;
    float bias = bc2[co];
    float part = 0.f;
    #pragma unroll
    for (int j = 0; j < 4; j++) {
      int opix = wv4*16 + g*4 + j;
      int oy = by*8 + (opix>>3), ox = bx*8 + (opix&7);
      float v = acc[ct][j] + bias;
      c2[((size_t)b*HWp + (size_t)oy*Ww + ox)*64 + co] = v;
      part += v;
    }
    part += __shfl_xor(part, 16);
    part += __shfl_xor(part, 32);
    if (g == 0) red[wv4][co] = part;
  }
  __syncthreads();
  if (threadIdx.x < 64) {
    float s = red[0][threadIdx.x] + red[1][threadIdx.x] + red[2][threadIdx.x] + red[3][threadIdx.x];
    atomicAdd(&sums[b*64 + threadIdx.x], s);
  }
}

// ------------------- K8: channel attention -------------------
__global__ void k_att(const float* __restrict__ sums,
                      const float* __restrict__ wd, const float* __restrict__ bd,
                      const float* __restrict__ wu, const float* __restrict__ bu,
                      float* __restrict__ att){
  int tid = threadIdx.x;            // 128 threads
  int b = tid >> 6, co = tid & 63;
  float inv = 1.f / (float)HWp;
  float hid[4];
  #pragma unroll
  for (int j = 0; j < 4; j++) {
    float acc = bd[j];
    for (int c = 0; c < 64; c++) acc += wd[j*64+c] * (sums[b*64+c] * inv);
    hid[j] = fmaxf(acc, 0.f);
  }
  float acc = bu[co];
  #pragma unroll
  for (int j = 0; j < 4; j++) acc += wu[co*4+j] * hid[j];
  att[tid] = 1.f / (1.f + __expf(-acc));
}

// ------------------- K9: final combine + NHWC -> NCHW -------------------
__global__ __launch_bounds__(256) void k_final(
    const float* __restrict__ x1, const float* __restrict__ c2,
    const float* __restrict__ skip2, const float* __restrict__ att,
    float* __restrict__ out){
  __shared__ float t[64][65];
  int b = blockIdx.x / WPB;
  int hw0 = (blockIdx.x % WPB) * 64;
  int lane = threadIdx.x & 63, grp = threadIdx.x >> 6;
  float sk = skip2[lane], at = att[b*64 + lane];
  #pragma unroll
  for (int r = 0; r < 64; r += 4) {
    int hwl = r + grp;
    size_t T = (size_t)b*HWp + hw0 + hwl;
    t[hwl][lane] = x1[T*64+lane]*sk + c2[T*64+lane]*at;
  }
  __syncthreads();
  float* ob = out + (size_t)b * Cch * HWp;
  #pragma unroll
  for (int r = 0; r < 64; r += 4) {
    int c = r + grp;
    ob[(size_t)c*HWp + hw0 + lane] = t[lane][c];
  }
}

extern "C" void kernel_launch(void* const* d_in, const int* in_sizes, int n_in,
                              void* d_out, int out_size, void* d_ws, size_t ws_size,
                              hipStream_t stream) {
  (void)in_sizes; (void)n_in; (void)out_size; (void)ws_size;
  const float* x      = (const float*)d_in[0];
  const float* ln1_g  = (const float*)d_in[1];
  const float* ln1_b  = (const float*)d_in[2];
  const float* in_w   = (const float*)d_in[3];
  const float* in_b   = (const float*)d_in[4];
  const float* conv_w = (const float*)d_in[5];
  const float* conv_b = (const float*)d_in[6];
  const float* xproj_w= (const float*)d_in[7];
  const float* dt_w   = (const float*)d_in[8];
  const float* dt_b   = (const float*)d_in[9];
  const float* A_log  = (const float*)d_in[10];
  const float* Dp     = (const float*)d_in[11];
  const float* out_w  = (const float*)d_in[12];
  const float* out_b  = (const float*)d_in[13];
  const float* skip1  = (const float*)d_in[14];
  const float* ln2_g  = (const float*)d_in[15];
  const float* ln2_b  = (const float*)d_in[16];
  const float* skip2  = (const float*)d_in[17];
  const float* cab_w1 = (const float*)d_in[18];
  const float* cab_b1 = (const float*)d_in[19];
  const float* cab_w2 = (const float*)d_in[20];
  const float* cab_b2 = (const float*)d_in[21];
  const float* ca_wd  = (const float*)d_in[22];
  const float* ca_bd  = (const float*)d_in[23];
  const float* ca_wu  = (const float*)d_in[24];
  const float* ca_bu  = (const float*)d_in[25];

  float* ws   = (float*)d_ws;
  float* xT   = ws;                        // [0, 4718592)
  float* xc   = ws + 4718592;              // g in-place; c2 aliases later
  float* z    = ws + 14155776;             // x1/x2 alias later
  float* dbc  = ws + 23592960;             // c1 aliases later
  float* sums = ws + 26247168;             // 128
  float* att  = ws + 26247296;             // 128
  float* x1   = ws + 14155776;             // alias over z
  float* x2   = ws + 18874368;             // alias over z second half
  __hip_bfloat16* c1 = (__hip_bfloat16*)(ws + 23592960); // alias over dbc
  float* c2   = ws + 4718592;              // alias over xc/g

  hipMemsetAsync(sums, 0, 128*sizeof(float), stream);
  k_transpose<<<NW, 256, 0, stream>>>(x, xT);
  k_stage1<<<NW, 256, 0, stream>>>(xT, ln1_g, ln1_b, in_w, in_b, conv_w, conv_b, xc, z);
  k_dbc<<<NW, 256, 0, stream>>>(xc, xproj_w, dbc);
  k_scan3<<<NW, 128, 0, stream>>>(xc, z, dbc, dt_w, dt_b, A_log, Dp);
  k_out<<<NW, 256, 0, stream>>>(xT, xc, out_w, out_b, skip1, ln2_g, ln2_b, x1, x2);
  k_conv1<<<NW, 256, 0, stream>>>(x2, cab_w1, cab_b1, c1);
  k_conv2<<<NW, 256, 0, stream>>>(c1, cab_w2, cab_b2, c2, sums);
  k_att<<<1, 128, 0, stream>>>(sums, ca_wd, ca_bd, ca_wu, ca_bu, att);
  k_final<<<NW, 256, 0, stream>>>(x1, c2, skip2, att, (float*)d_out);
}